// Round 10
// baseline (99.403 us; speedup 1.0000x reference)
//
#include <hip/hip_runtime.h>
#include <math.h>

#define BB 4
#define NN 4096
#define MM 4096
#define TI 128
#define TJ 128
#define NTI (NN / TI)   // 32
#define NTJ (MM / TJ)   // 32

#define L2E100 144.26950408889634f   // 100*log2(e); exp(-100 d) = exp2(-L2E100 d)

// ---------- cross-lane helpers ----------
__device__ __forceinline__ float dpp_sum16(float v) {
    float t;
    t = __int_as_float(__builtin_amdgcn_update_dpp(0, __float_as_int(v), 0x111, 0xF, 0xF, true)); v += t;
    t = __int_as_float(__builtin_amdgcn_update_dpp(0, __float_as_int(v), 0x112, 0xF, 0xF, true)); v += t;
    t = __int_as_float(__builtin_amdgcn_update_dpp(0, __float_as_int(v), 0x114, 0xF, 0xF, true)); v += t;
    t = __int_as_float(__builtin_amdgcn_update_dpp(0, __float_as_int(v), 0x118, 0xF, 0xF, true)); v += t;
    return v;  // total in lane (tx==15)
}
__device__ __forceinline__ float dpp_min16(float v) {
    float t;
    t = __int_as_float(__builtin_amdgcn_update_dpp(__float_as_int(v), __float_as_int(v), 0x111, 0xF, 0xF, false)); v = fminf(v, t);
    t = __int_as_float(__builtin_amdgcn_update_dpp(__float_as_int(v), __float_as_int(v), 0x112, 0xF, 0xF, false)); v = fminf(v, t);
    t = __int_as_float(__builtin_amdgcn_update_dpp(__float_as_int(v), __float_as_int(v), 0x114, 0xF, 0xF, false)); v = fminf(v, t);
    t = __int_as_float(__builtin_amdgcn_update_dpp(__float_as_int(v), __float_as_int(v), 0x118, 0xF, 0xF, false)); v = fminf(v, t);
    return v;  // min in lane (tx==15)
}
__device__ __forceinline__ float bperm(float v, int addr) {
    return __int_as_float(__builtin_amdgcn_ds_bpermute(addr, __float_as_int(v)));
}

// ---------- staging: X=(-2x,|x|^2), Y=(y,|y|^2); d2 = X.Y + (Xw+Yw) ----------
__device__ __forceinline__ float4 stage_x(const float* p) {
    float a = p[0], b = p[1], c = p[2];
    float4 r; r.x = -2.0f * a; r.y = -2.0f * b; r.z = -2.0f * c;
    r.w = fmaf(a, a, fmaf(b, b, c * c));
    return r;
}
__device__ __forceinline__ float4 stage_y(const float* p) {
    float a = p[0], b = p[1], c = p[2];
    float4 r; r.x = a; r.y = b; r.z = c;
    r.w = fmaf(a, a, fmaf(b, b, c * c));
    return r;
}

// ---------- asm inner blocks, "+v"-threaded persistent state (no remat) ----------
__device__ __forceinline__ void p1_pair2(
    float& Xx, float& Xy, float& Xz, float& Xw,
    float& YxA, float& YyA, float& YzA, float& YwA,
    float& YxB, float& YyB, float& YzB, float& YwB,
    float& rmin, float& cminA, float& cminB)
{
    float pqA, pqB;
    asm("v_add_f32 %[pqA], %[Xw], %[YwA]\n\t"
        "v_add_f32 %[pqB], %[Xw], %[YwB]\n\t"
        "v_fmac_f32 %[pqA], %[Xz], %[YzA]\n\t"
        "v_fmac_f32 %[pqB], %[Xz], %[YzB]\n\t"
        "v_fmac_f32 %[pqA], %[Xy], %[YyA]\n\t"
        "v_fmac_f32 %[pqB], %[Xy], %[YyB]\n\t"
        "v_fmac_f32 %[pqA], %[Xx], %[YxA]\n\t"
        "v_fmac_f32 %[pqB], %[Xx], %[YxB]\n\t"
        "v_min_f32 %[rmin], %[rmin], %[pqA]\n\t"
        "v_min_f32 %[cminA], %[cminA], %[pqA]\n\t"
        "v_min_f32 %[rmin], %[rmin], %[pqB]\n\t"
        "v_min_f32 %[cminB], %[cminB], %[pqB]"
        : [pqA]"=&v"(pqA), [pqB]"=&v"(pqB),
          [rmin]"+v"(rmin), [cminA]"+v"(cminA), [cminB]"+v"(cminB),
          [Xx]"+v"(Xx), [Xy]"+v"(Xy), [Xz]"+v"(Xz), [Xw]"+v"(Xw),
          [YxA]"+v"(YxA), [YyA]"+v"(YyA), [YzA]"+v"(YzA), [YwA]"+v"(YwA),
          [YxB]"+v"(YxB), [YyB]"+v"(YyB), [YzB]"+v"(YzB), [YwB]"+v"(YwB));
}

// pass2: 28 instr / 2 pairs = 22 VALU + 6 trans.
__device__ __forceinline__ void p2_pair2(
    float& Xx, float& Xy, float& Xz, float& Xw, float& srk,
    float& YxA, float& YyA, float& YzA, float& YwA, float& scA,
    float& YxB, float& YyB, float& YzB, float& YwB, float& scB,
    float nL,
    float& nr, float& dr, float& ncA, float& dcA, float& ncB, float& dcB)
{
    float pqA, pqB, dA, dB, eA, eB;
    asm("v_add_f32 %[pqA], %[Xw], %[YwA]\n\t"
        "v_add_f32 %[pqB], %[Xw], %[YwB]\n\t"
        "v_fmac_f32 %[pqA], %[Xz], %[YzA]\n\t"
        "v_fmac_f32 %[pqB], %[Xz], %[YzB]\n\t"
        "v_fmac_f32 %[pqA], %[Xy], %[YyA]\n\t"
        "v_fmac_f32 %[pqB], %[Xy], %[YyB]\n\t"
        "v_fmac_f32 %[pqA], %[Xx], %[YxA]\n\t"
        "v_fmac_f32 %[pqB], %[Xx], %[YxB]\n\t"
        "v_max_f32 %[pqA], 0, %[pqA]\n\t"
        "v_max_f32 %[pqB], 0, %[pqB]\n\t"
        "v_sqrt_f32 %[dA], %[pqA]\n\t"
        "v_sqrt_f32 %[dB], %[pqB]\n\t"
        "v_fma_f32 %[eA], %[dA], %[nL], %[srk]\n\t"
        "v_fma_f32 %[eB], %[dB], %[nL], %[srk]\n\t"
        "v_exp_f32 %[eA], %[eA]\n\t"
        "v_exp_f32 %[eB], %[eB]\n\t"
        "v_fmac_f32 %[nr], %[dA], %[eA]\n\t"
        "v_add_f32 %[dr], %[dr], %[eA]\n\t"
        "v_fmac_f32 %[nr], %[dB], %[eB]\n\t"
        "v_add_f32 %[dr], %[dr], %[eB]\n\t"
        "v_fma_f32 %[eA], %[dA], %[nL], %[scA]\n\t"
        "v_fma_f32 %[eB], %[dB], %[nL], %[scB]\n\t"
        "v_exp_f32 %[eA], %[eA]\n\t"
        "v_exp_f32 %[eB], %[eB]\n\t"
        "v_fmac_f32 %[ncA], %[dA], %[eA]\n\t"
        "v_add_f32 %[dcA], %[dcA], %[eA]\n\t"
        "v_fmac_f32 %[ncB], %[dB], %[eB]\n\t"
        "v_add_f32 %[dcB], %[dcB], %[eB]"
        : [pqA]"=&v"(pqA), [pqB]"=&v"(pqB), [dA]"=&v"(dA), [dB]"=&v"(dB),
          [eA]"=&v"(eA), [eB]"=&v"(eB),
          [nr]"+v"(nr), [dr]"+v"(dr),
          [ncA]"+v"(ncA), [dcA]"+v"(dcA), [ncB]"+v"(ncB), [dcB]"+v"(dcB),
          [Xx]"+v"(Xx), [Xy]"+v"(Xy), [Xz]"+v"(Xz), [Xw]"+v"(Xw), [srk]"+v"(srk),
          [YxA]"+v"(YxA), [YyA]"+v"(YyA), [YzA]"+v"(YzA), [YwA]"+v"(YwA), [scA]"+v"(scA),
          [YxB]"+v"(YxB), [YyB]"+v"(YyB), [YzB]"+v"(YzB), [YwB]"+v"(YwB), [scB]"+v"(scB)
        : [nL]"s"(nL));
}

// workspace layout (floats): see R1.
__global__ __launch_bounds__(256)
void init_ws_kernel(float* ws, float* out) {
    int idx = blockIdx.x * 256 + threadIdx.x;
    if (idx < 2 * 16384) ws[idx] = 1e30f;
    else if (idx < 6 * 16384) ws[idx] = 0.0f;
    if (idx == 0) out[0] = 0.0f;
}

// LDS padded to ~57KB/block -> hard 2 blocks/CU = 2 waves/EU. Occupancy is
// LDS-pinned, so the register allocator has ZERO incentive to economize arch
// VGPRs (R2-R9: with small LDS it caps arch at ~40-56 and shuttles the rest
// through AGPRs, inflating VALU ~35%). waves_per_eu(2,2) makes the 256-reg
// budget explicit. Tell-tale: VGPR_Count must jump >100.
__global__ __launch_bounds__(256) __attribute__((amdgpu_waves_per_eu(2, 2)))
void pass1_min(const float* __restrict__ x, const float* __restrict__ y,
               unsigned int* __restrict__ m2_row, unsigned int* __restrict__ m2_col) {
    const int bid = blockIdx.x;
    const int b   = bid / (NTI * NTJ);
    const int rem = bid % (NTI * NTJ);
    const int i0  = (rem / NTJ) * TI;
    const int j0  = (rem % NTJ) * TJ;

    __shared__ float4 xs4[TI];
    __shared__ float4 ys4[TJ];
    __shared__ float  redbuf[13568];   // [0,512): cm per-wave slots; rest = occupancy pad

    const int t = threadIdx.x;
    if (t < TI) xs4[t] = stage_x(&x[(size_t)(b * NN + i0 + t) * 3]);
    else        ys4[t - TI] = stage_y(&y[(size_t)(b * MM + j0 + (t - TI)) * 3]);
    __syncthreads();

    const int tx = t & 15, ty = t >> 4;
    const int lane = t & 63, wv = t >> 6;
    float Yx[8], Yy[8], Yz[8], Yw[8], cmin[8];
#pragma unroll
    for (int l = 0; l < 8; ++l) {
        float4 v = ys4[tx + l * 16];
        Yx[l] = v.x; Yy[l] = v.y; Yz[l] = v.z; Yw[l] = v.w;
        cmin[l] = 1e30f;
    }

#pragma unroll
    for (int k = 0; k < 8; ++k) {
        float4 Xv = xs4[ty + k * 16];
        float Xx = Xv.x, Xy = Xv.y, Xz = Xv.z, Xw = Xv.w;
        float rmin = 1e30f;
#pragma unroll
        for (int l = 0; l < 8; l += 2) {
            p1_pair2(Xx, Xy, Xz, Xw,
                     Yx[l], Yy[l], Yz[l], Yw[l],
                     Yx[l+1], Yy[l+1], Yz[l+1], Yw[l+1],
                     rmin, cmin[l], cmin[l + 1]);
        }
        rmin = dpp_min16(rmin);
        if (tx == 15) atomicMin(&m2_row[b * NN + i0 + ty + k * 16], __float_as_uint(rmin));
    }

    const int a16 = (lane ^ 16) << 2, a32 = (lane ^ 32) << 2;
#pragma unroll
    for (int l = 0; l < 8; ++l) {
        float v = cmin[l];
        v = fminf(v, bperm(v, a16));
        v = fminf(v, bperm(v, a32));
        if (lane < 16) redbuf[wv * TJ + lane + l * 16] = v;
    }
    __syncthreads();
    if (t < TJ) {
        float m = fminf(fminf(redbuf[t], redbuf[TJ + t]),
                        fminf(redbuf[2 * TJ + t], redbuf[3 * TJ + t]));
        atomicMin(&m2_col[b * MM + j0 + t], __float_as_uint(m));
    }
}

__global__ __launch_bounds__(256) __attribute__((amdgpu_waves_per_eu(2, 2)))
void pass2_acc(const float* __restrict__ x, const float* __restrict__ y,
               const unsigned int* __restrict__ m2_row, const unsigned int* __restrict__ m2_col,
               float* __restrict__ num_r, float* __restrict__ den_r,
               float* __restrict__ num_c, float* __restrict__ den_c) {
    const int bid = blockIdx.x;
    const int b   = bid / (NTI * NTJ);
    const int rem = bid % (NTI * NTJ);
    const int i0  = (rem / NTJ) * TI;
    const int j0  = (rem % NTJ) * TJ;

    __shared__ float4 xs4[TI];
    __shared__ float4 ys4[TJ];
    __shared__ float  ar[TI];
    __shared__ float  ac[TJ];
    __shared__ float  redbuf[13312];   // [0,512): sn slots; [2048,2560): sd slots; rest pad

    const int t = threadIdx.x;
    if (t < TI) {
        xs4[t] = stage_x(&x[(size_t)(b * NN + i0 + t) * 3]);
        ar[t]  = L2E100 * __builtin_amdgcn_sqrtf(fmaxf(__uint_as_float(m2_row[b * NN + i0 + t]), 0.0f));
    } else {
        int j = t - TI;
        ys4[j] = stage_y(&y[(size_t)(b * MM + j0 + j) * 3]);
        ac[j]  = L2E100 * __builtin_amdgcn_sqrtf(fmaxf(__uint_as_float(m2_col[b * MM + j0 + j]), 0.0f));
    }
    __syncthreads();

    const int tx = t & 15, ty = t >> 4;
    const int lane = t & 63, wv = t >> 6;
    const float nL = -L2E100;

    float Yx[8], Yy[8], Yz[8], Yw[8], sc[8], nc[8], dc[8];
#pragma unroll
    for (int l = 0; l < 8; ++l) {
        float4 v = ys4[tx + l * 16];
        Yx[l] = v.x; Yy[l] = v.y; Yz[l] = v.z; Yw[l] = v.w;
        sc[l] = ac[tx + l * 16];
        nc[l] = 0.0f; dc[l] = 0.0f;
    }

#pragma unroll
    for (int k = 0; k < 8; ++k) {
        float4 Xv = xs4[ty + k * 16];
        float Xx = Xv.x, Xy = Xv.y, Xz = Xv.z, Xw = Xv.w;
        float srk = ar[ty + k * 16];
        float nr = 0.0f, dr = 0.0f;
#pragma unroll
        for (int l = 0; l < 8; l += 2) {
            p2_pair2(Xx, Xy, Xz, Xw, srk,
                     Yx[l], Yy[l], Yz[l], Yw[l], sc[l],
                     Yx[l+1], Yy[l+1], Yz[l+1], Yw[l+1], sc[l+1],
                     nL, nr, dr, nc[l], dc[l], nc[l + 1], dc[l + 1]);
        }
        float vn = dpp_sum16(nr);
        float vd = dpp_sum16(dr);
        if (tx == 15) {
            atomicAdd(&num_r[b * NN + i0 + ty + k * 16], vn);
            atomicAdd(&den_r[b * NN + i0 + ty + k * 16], vd);
        }
    }

    const int a16 = (lane ^ 16) << 2, a32 = (lane ^ 32) << 2;
#pragma unroll
    for (int l = 0; l < 8; ++l) {
        float vn = nc[l], vd = dc[l];
        vn += bperm(vn, a16); vd += bperm(vd, a16);
        vn += bperm(vn, a32); vd += bperm(vd, a32);
        if (lane < 16) {
            redbuf[wv * TJ + lane + l * 16] = vn;
            redbuf[2048 + wv * TJ + lane + l * 16] = vd;
        }
    }
    __syncthreads();
    if (t < TJ) {
        float ns = (redbuf[t] + redbuf[TJ + t]) + (redbuf[2 * TJ + t] + redbuf[3 * TJ + t]);
        float ds = (redbuf[2048 + t] + redbuf[2048 + TJ + t])
                 + (redbuf[2048 + 2 * TJ + t] + redbuf[2048 + 3 * TJ + t]);
        atomicAdd(&num_c[b * MM + j0 + t], ns);
        atomicAdd(&den_c[b * MM + j0 + t], ds);
    }
}

__global__ __launch_bounds__(256)
void finalize_kernel(const float* __restrict__ num_r, const float* __restrict__ den_r,
                     const float* __restrict__ num_c, const float* __restrict__ den_c,
                     float* __restrict__ out) {
    const int gid = blockIdx.x * 256 + threadIdx.x;
    float s = 0.0f;
    for (int idx = gid; idx < BB * NN; idx += 32 * 256) {
        s = fmaf(num_r[idx], __builtin_amdgcn_rcpf(den_r[idx]), s);
        s = fmaf(num_c[idx], __builtin_amdgcn_rcpf(den_c[idx]), s);
    }
#pragma unroll
    for (int m = 1; m < 64; m <<= 1) s += __shfl_xor(s, m);
    __shared__ float wsum[4];
    const int t = threadIdx.x;
    if ((t & 63) == 0) wsum[t >> 6] = s;
    __syncthreads();
    if (t == 0) {
        float v = (wsum[0] + wsum[1] + wsum[2] + wsum[3]) * (1.0f / (float)(BB * NN));
        atomicAdd(out, v);
    }
}

extern "C" void kernel_launch(void* const* d_in, const int* in_sizes, int n_in,
                              void* d_out, int out_size, void* d_ws, size_t ws_size,
                              hipStream_t stream) {
    const float* x = (const float*)d_in[0];
    const float* y = (const float*)d_in[1];
    float* ws = (float*)d_ws;

    unsigned int* m2_row = (unsigned int*)(ws);
    unsigned int* m2_col = (unsigned int*)(ws + 16384);
    float* num_r = ws + 32768;
    float* den_r = ws + 49152;
    float* num_c = ws + 65536;
    float* den_c = ws + 81920;

    hipLaunchKernelGGL(init_ws_kernel, dim3(384), dim3(256), 0, stream, ws, (float*)d_out);
    dim3 grid(BB * NTI * NTJ);  // 4096 blocks
    hipLaunchKernelGGL(pass1_min, grid, dim3(256), 0, stream, x, y, m2_row, m2_col);
    hipLaunchKernelGGL(pass2_acc, grid, dim3(256), 0, stream,
                       x, y, m2_row, m2_col, num_r, den_r, num_c, den_c);
    hipLaunchKernelGGL(finalize_kernel, dim3(32), dim3(256), 0, stream,
                       num_r, den_r, num_c, den_c, (float*)d_out);
}

// Round 13
// 68.870 us; speedup vs baseline: 1.4433x; 1.4433x over previous
//
#include <hip/hip_runtime.h>
#include <math.h>

#define BB 4
#define NN 4096
#define MM 4096
#define TI 128
#define TJ 128
#define NTI (NN / TI)   // 32
#define NTJ (MM / TJ)   // 32

#define L2E100 144.26950408889634f   // 100*log2(e); exp(-100 d) = exp2(-L2E100 d)

// ---------- cross-lane helpers ----------
__device__ __forceinline__ float dpp_sum16(float v) {
    float t;
    t = __int_as_float(__builtin_amdgcn_update_dpp(0, __float_as_int(v), 0x111, 0xF, 0xF, true)); v += t;
    t = __int_as_float(__builtin_amdgcn_update_dpp(0, __float_as_int(v), 0x112, 0xF, 0xF, true)); v += t;
    t = __int_as_float(__builtin_amdgcn_update_dpp(0, __float_as_int(v), 0x114, 0xF, 0xF, true)); v += t;
    t = __int_as_float(__builtin_amdgcn_update_dpp(0, __float_as_int(v), 0x118, 0xF, 0xF, true)); v += t;
    return v;  // total in lane (tx==15)
}
__device__ __forceinline__ float dpp_min16(float v) {
    float t;
    t = __int_as_float(__builtin_amdgcn_update_dpp(__float_as_int(v), __float_as_int(v), 0x111, 0xF, 0xF, false)); v = fminf(v, t);
    t = __int_as_float(__builtin_amdgcn_update_dpp(__float_as_int(v), __float_as_int(v), 0x112, 0xF, 0xF, false)); v = fminf(v, t);
    t = __int_as_float(__builtin_amdgcn_update_dpp(__float_as_int(v), __float_as_int(v), 0x114, 0xF, 0xF, false)); v = fminf(v, t);
    t = __int_as_float(__builtin_amdgcn_update_dpp(__float_as_int(v), __float_as_int(v), 0x118, 0xF, 0xF, false)); v = fminf(v, t);
    return v;  // min in lane (tx==15)
}
__device__ __forceinline__ float bperm(float v, int addr) {
    return __int_as_float(__builtin_amdgcn_ds_bpermute(addr, __float_as_int(v)));
}

// ---------- staging: X=(-2x,|x|^2), Y=(y,|y|^2); d2 = X.Y + (Xw+Yw) ----------
__device__ __forceinline__ float4 stage_x(const float* p) {
    float a = p[0], b = p[1], c = p[2];
    float4 r; r.x = -2.0f * a; r.y = -2.0f * b; r.z = -2.0f * c;
    r.w = fmaf(a, a, fmaf(b, b, c * c));
    return r;
}
__device__ __forceinline__ float4 stage_y(const float* p) {
    float a = p[0], b = p[1], c = p[2];
    float4 r; r.x = a; r.y = b; r.z = c;
    r.w = fmaf(a, a, fmaf(b, b, c * c));
    return r;
}

// ---------- 4-pair asm blocks: 4-way chain interleave ----------
// Every trans result has 3 intervening trans ops (~48 cyc) before its
// consumer; "+v"-threaded persistent state (R6-R8: prevents LDS remat).

// pass1: 24 instr / 4 pairs.
__device__ __forceinline__ void p1_quad(
    float& Xx, float& Xy, float& Xz, float& Xw,
    float& YxA, float& YyA, float& YzA, float& YwA,
    float& YxB, float& YyB, float& YzB, float& YwB,
    float& YxC, float& YyC, float& YzC, float& YwC,
    float& YxD, float& YyD, float& YzD, float& YwD,
    float& rm, float& cmA, float& cmB, float& cmC, float& cmD)
{
    float pA, pB, pC, pD;
    asm("v_add_f32 %[pA], %[Xw], %[YwA]\n\t"
        "v_add_f32 %[pB], %[Xw], %[YwB]\n\t"
        "v_add_f32 %[pC], %[Xw], %[YwC]\n\t"
        "v_add_f32 %[pD], %[Xw], %[YwD]\n\t"
        "v_fmac_f32 %[pA], %[Xz], %[YzA]\n\t"
        "v_fmac_f32 %[pB], %[Xz], %[YzB]\n\t"
        "v_fmac_f32 %[pC], %[Xz], %[YzC]\n\t"
        "v_fmac_f32 %[pD], %[Xz], %[YzD]\n\t"
        "v_fmac_f32 %[pA], %[Xy], %[YyA]\n\t"
        "v_fmac_f32 %[pB], %[Xy], %[YyB]\n\t"
        "v_fmac_f32 %[pC], %[Xy], %[YyC]\n\t"
        "v_fmac_f32 %[pD], %[Xy], %[YyD]\n\t"
        "v_fmac_f32 %[pA], %[Xx], %[YxA]\n\t"
        "v_fmac_f32 %[pB], %[Xx], %[YxB]\n\t"
        "v_fmac_f32 %[pC], %[Xx], %[YxC]\n\t"
        "v_fmac_f32 %[pD], %[Xx], %[YxD]\n\t"
        "v_min_f32 %[rm], %[rm], %[pA]\n\t"
        "v_min_f32 %[cmA], %[cmA], %[pA]\n\t"
        "v_min_f32 %[rm], %[rm], %[pB]\n\t"
        "v_min_f32 %[cmB], %[cmB], %[pB]\n\t"
        "v_min_f32 %[rm], %[rm], %[pC]\n\t"
        "v_min_f32 %[cmC], %[cmC], %[pC]\n\t"
        "v_min_f32 %[rm], %[rm], %[pD]\n\t"
        "v_min_f32 %[cmD], %[cmD], %[pD]"
        : [pA]"=&v"(pA), [pB]"=&v"(pB), [pC]"=&v"(pC), [pD]"=&v"(pD),
          [rm]"+v"(rm), [cmA]"+v"(cmA), [cmB]"+v"(cmB), [cmC]"+v"(cmC), [cmD]"+v"(cmD),
          [Xx]"+v"(Xx), [Xy]"+v"(Xy), [Xz]"+v"(Xz), [Xw]"+v"(Xw),
          [YxA]"+v"(YxA), [YyA]"+v"(YyA), [YzA]"+v"(YzA), [YwA]"+v"(YwA),
          [YxB]"+v"(YxB), [YyB]"+v"(YyB), [YzB]"+v"(YzB), [YwB]"+v"(YwB),
          [YxC]"+v"(YxC), [YyC]"+v"(YyC), [YzC]"+v"(YzC), [YwC]"+v"(YwC),
          [YxD]"+v"(YxD), [YyD]"+v"(YyD), [YzD]"+v"(YzD), [YwD]"+v"(YwD));
}

// pass2: 56 instr / 4 pairs (14/pair). sqrt in-place into p (=d).
__device__ __forceinline__ void p2_quad(
    float& Xx, float& Xy, float& Xz, float& Xw, float& sr,
    float& YxA, float& YyA, float& YzA, float& YwA, float& scA,
    float& YxB, float& YyB, float& YzB, float& YwB, float& scB,
    float& YxC, float& YyC, float& YzC, float& YwC, float& scC,
    float& YxD, float& YyD, float& YzD, float& YwD, float& scD,
    float nL,
    float& nr, float& dr,
    float& ncA, float& dcA, float& ncB, float& dcB,
    float& ncC, float& dcC, float& ncD, float& dcD)
{
    float pA, pB, pC, pD, eA, eB, eC, eD;
    asm("v_add_f32 %[pA], %[Xw], %[YwA]\n\t"
        "v_add_f32 %[pB], %[Xw], %[YwB]\n\t"
        "v_add_f32 %[pC], %[Xw], %[YwC]\n\t"
        "v_add_f32 %[pD], %[Xw], %[YwD]\n\t"
        "v_fmac_f32 %[pA], %[Xz], %[YzA]\n\t"
        "v_fmac_f32 %[pB], %[Xz], %[YzB]\n\t"
        "v_fmac_f32 %[pC], %[Xz], %[YzC]\n\t"
        "v_fmac_f32 %[pD], %[Xz], %[YzD]\n\t"
        "v_fmac_f32 %[pA], %[Xy], %[YyA]\n\t"
        "v_fmac_f32 %[pB], %[Xy], %[YyB]\n\t"
        "v_fmac_f32 %[pC], %[Xy], %[YyC]\n\t"
        "v_fmac_f32 %[pD], %[Xy], %[YyD]\n\t"
        "v_fmac_f32 %[pA], %[Xx], %[YxA]\n\t"
        "v_fmac_f32 %[pB], %[Xx], %[YxB]\n\t"
        "v_fmac_f32 %[pC], %[Xx], %[YxC]\n\t"
        "v_fmac_f32 %[pD], %[Xx], %[YxD]\n\t"
        "v_max_f32 %[pA], 0, %[pA]\n\t"
        "v_max_f32 %[pB], 0, %[pB]\n\t"
        "v_max_f32 %[pC], 0, %[pC]\n\t"
        "v_max_f32 %[pD], 0, %[pD]\n\t"
        "v_sqrt_f32 %[pA], %[pA]\n\t"
        "v_sqrt_f32 %[pB], %[pB]\n\t"
        "v_sqrt_f32 %[pC], %[pC]\n\t"
        "v_sqrt_f32 %[pD], %[pD]\n\t"
        "v_fma_f32 %[eA], %[pA], %[nL], %[sr]\n\t"
        "v_fma_f32 %[eB], %[pB], %[nL], %[sr]\n\t"
        "v_fma_f32 %[eC], %[pC], %[nL], %[sr]\n\t"
        "v_fma_f32 %[eD], %[pD], %[nL], %[sr]\n\t"
        "v_exp_f32 %[eA], %[eA]\n\t"
        "v_exp_f32 %[eB], %[eB]\n\t"
        "v_exp_f32 %[eC], %[eC]\n\t"
        "v_exp_f32 %[eD], %[eD]\n\t"
        "v_fmac_f32 %[nr], %[pA], %[eA]\n\t"
        "v_add_f32 %[dr], %[dr], %[eA]\n\t"
        "v_fma_f32 %[eA], %[pA], %[nL], %[scA]\n\t"
        "v_fmac_f32 %[nr], %[pB], %[eB]\n\t"
        "v_add_f32 %[dr], %[dr], %[eB]\n\t"
        "v_fma_f32 %[eB], %[pB], %[nL], %[scB]\n\t"
        "v_fmac_f32 %[nr], %[pC], %[eC]\n\t"
        "v_add_f32 %[dr], %[dr], %[eC]\n\t"
        "v_fma_f32 %[eC], %[pC], %[nL], %[scC]\n\t"
        "v_fmac_f32 %[nr], %[pD], %[eD]\n\t"
        "v_add_f32 %[dr], %[dr], %[eD]\n\t"
        "v_fma_f32 %[eD], %[pD], %[nL], %[scD]\n\t"
        "v_exp_f32 %[eA], %[eA]\n\t"
        "v_exp_f32 %[eB], %[eB]\n\t"
        "v_exp_f32 %[eC], %[eC]\n\t"
        "v_exp_f32 %[eD], %[eD]\n\t"
        "v_fmac_f32 %[ncA], %[pA], %[eA]\n\t"
        "v_add_f32 %[dcA], %[dcA], %[eA]\n\t"
        "v_fmac_f32 %[ncB], %[pB], %[eB]\n\t"
        "v_add_f32 %[dcB], %[dcB], %[eB]\n\t"
        "v_fmac_f32 %[ncC], %[pC], %[eC]\n\t"
        "v_add_f32 %[dcC], %[dcC], %[eC]\n\t"
        "v_fmac_f32 %[ncD], %[pD], %[eD]\n\t"
        "v_add_f32 %[dcD], %[dcD], %[eD]"
        : [pA]"=&v"(pA), [pB]"=&v"(pB), [pC]"=&v"(pC), [pD]"=&v"(pD),
          [eA]"=&v"(eA), [eB]"=&v"(eB), [eC]"=&v"(eC), [eD]"=&v"(eD),
          [nr]"+v"(nr), [dr]"+v"(dr),
          [ncA]"+v"(ncA), [dcA]"+v"(dcA), [ncB]"+v"(ncB), [dcB]"+v"(dcB),
          [ncC]"+v"(ncC), [dcC]"+v"(dcC), [ncD]"+v"(ncD), [dcD]"+v"(dcD),
          [Xx]"+v"(Xx), [Xy]"+v"(Xy), [Xz]"+v"(Xz), [Xw]"+v"(Xw), [sr]"+v"(sr),
          [YxA]"+v"(YxA), [YyA]"+v"(YyA), [YzA]"+v"(YzA), [YwA]"+v"(YwA), [scA]"+v"(scA),
          [YxB]"+v"(YxB), [YyB]"+v"(YyB), [YzB]"+v"(YzB), [YwB]"+v"(YwB), [scB]"+v"(scB),
          [YxC]"+v"(YxC), [YyC]"+v"(YyC), [YzC]"+v"(YzC), [YwC]"+v"(YwC), [scC]"+v"(scC),
          [YxD]"+v"(YxD), [YyD]"+v"(YyD), [YzD]"+v"(YzD), [YwD]"+v"(YwD), [scD]"+v"(scD)
        : [nL]"s"(nL));
}

// workspace layout (floats): see R1.
__global__ __launch_bounds__(256)
void init_ws_kernel(float* ws, float* out) {
    int idx = blockIdx.x * 256 + threadIdx.x;
    if (idx < 2 * 16384) ws[idx] = 1e30f;
    else if (idx < 6 * 16384) ws[idx] = 0.0f;
    if (idx == 0) out[0] = 0.0f;
}

__global__ __launch_bounds__(256)
void pass1_min(const float* __restrict__ x, const float* __restrict__ y,
               unsigned int* __restrict__ m2_row, unsigned int* __restrict__ m2_col) {
    const int bid = blockIdx.x;
    const int b   = bid / (NTI * NTJ);
    const int rem = bid % (NTI * NTJ);
    const int i0  = (rem / NTJ) * TI;
    const int j0  = (rem % NTJ) * TJ;

    __shared__ float4 xs4[TI];
    __shared__ float4 ys4[TJ];
    __shared__ float  cm_w[4][TJ];

    const int t = threadIdx.x;
    if (t < TI) xs4[t] = stage_x(&x[(size_t)(b * NN + i0 + t) * 3]);
    else        ys4[t - TI] = stage_y(&y[(size_t)(b * MM + j0 + (t - TI)) * 3]);
    __syncthreads();

    const int tx = t & 15, ty = t >> 4;
    const int lane = t & 63, wv = t >> 6;
    float Yx[8], Yy[8], Yz[8], Yw[8], cmin[8];
#pragma unroll
    for (int l = 0; l < 8; ++l) {
        float4 v = ys4[tx + l * 16];
        Yx[l] = v.x; Yy[l] = v.y; Yz[l] = v.z; Yw[l] = v.w;
        cmin[l] = 1e30f;
    }

#pragma unroll
    for (int k = 0; k < 8; ++k) {
        float4 Xv = xs4[ty + k * 16];
        float Xx = Xv.x, Xy = Xv.y, Xz = Xv.z, Xw = Xv.w;
        float rmin = 1e30f;
#pragma unroll
        for (int l = 0; l < 8; l += 4) {
            p1_quad(Xx, Xy, Xz, Xw,
                    Yx[l], Yy[l], Yz[l], Yw[l],
                    Yx[l+1], Yy[l+1], Yz[l+1], Yw[l+1],
                    Yx[l+2], Yy[l+2], Yz[l+2], Yw[l+2],
                    Yx[l+3], Yy[l+3], Yz[l+3], Yw[l+3],
                    rmin, cmin[l], cmin[l+1], cmin[l+2], cmin[l+3]);
        }
        rmin = dpp_min16(rmin);
        if (tx == 15) atomicMin(&m2_row[b * NN + i0 + ty + k * 16], __float_as_uint(rmin));
    }

    const int a16 = (lane ^ 16) << 2, a32 = (lane ^ 32) << 2;
#pragma unroll
    for (int l = 0; l < 8; ++l) {
        float v = cmin[l];
        v = fminf(v, bperm(v, a16));
        v = fminf(v, bperm(v, a32));
        if (lane < 16) cm_w[wv][lane + l * 16] = v;
    }
    __syncthreads();
    if (t < TJ) {
        float m = fminf(fminf(cm_w[0][t], cm_w[1][t]), fminf(cm_w[2][t], cm_w[3][t]));
        atomicMin(&m2_col[b * MM + j0 + t], __float_as_uint(m));
    }
}

__global__ __launch_bounds__(256)
void pass2_acc(const float* __restrict__ x, const float* __restrict__ y,
               const unsigned int* __restrict__ m2_row, const unsigned int* __restrict__ m2_col,
               float* __restrict__ num_r, float* __restrict__ den_r,
               float* __restrict__ num_c, float* __restrict__ den_c) {
    const int bid = blockIdx.x;
    const int b   = bid / (NTI * NTJ);
    const int rem = bid % (NTI * NTJ);
    const int i0  = (rem / NTJ) * TI;
    const int j0  = (rem % NTJ) * TJ;

    __shared__ float4 xs4[TI];
    __shared__ float4 ys4[TJ];
    __shared__ float  ar[TI];
    __shared__ float  ac[TJ];
    __shared__ float  sn_w[4][TJ];
    __shared__ float  sd_w[4][TJ];

    const int t = threadIdx.x;
    if (t < TI) {
        xs4[t] = stage_x(&x[(size_t)(b * NN + i0 + t) * 3]);
        ar[t]  = L2E100 * __builtin_amdgcn_sqrtf(fmaxf(__uint_as_float(m2_row[b * NN + i0 + t]), 0.0f));
    } else {
        int j = t - TI;
        ys4[j] = stage_y(&y[(size_t)(b * MM + j0 + j) * 3]);
        ac[j]  = L2E100 * __builtin_amdgcn_sqrtf(fmaxf(__uint_as_float(m2_col[b * MM + j0 + j]), 0.0f));
    }
    __syncthreads();

    const int tx = t & 15, ty = t >> 4;
    const int lane = t & 63, wv = t >> 6;
    const float nL = -L2E100;

    float Yx[8], Yy[8], Yz[8], Yw[8], sc[8], nc[8], dc[8];
#pragma unroll
    for (int l = 0; l < 8; ++l) {
        float4 v = ys4[tx + l * 16];
        Yx[l] = v.x; Yy[l] = v.y; Yz[l] = v.z; Yw[l] = v.w;
        sc[l] = ac[tx + l * 16];
        nc[l] = 0.0f; dc[l] = 0.0f;
    }

#pragma unroll
    for (int k = 0; k < 8; ++k) {
        float4 Xv = xs4[ty + k * 16];
        float Xx = Xv.x, Xy = Xv.y, Xz = Xv.z, Xw = Xv.w;
        float srk = ar[ty + k * 16];
        float nr = 0.0f, dr = 0.0f;
#pragma unroll
        for (int l = 0; l < 8; l += 4) {
            p2_quad(Xx, Xy, Xz, Xw, srk,
                    Yx[l], Yy[l], Yz[l], Yw[l], sc[l],
                    Yx[l+1], Yy[l+1], Yz[l+1], Yw[l+1], sc[l+1],
                    Yx[l+2], Yy[l+2], Yz[l+2], Yw[l+2], sc[l+2],
                    Yx[l+3], Yy[l+3], Yz[l+3], Yw[l+3], sc[l+3],
                    nL, nr, dr,
                    nc[l], dc[l], nc[l+1], dc[l+1],
                    nc[l+2], dc[l+2], nc[l+3], dc[l+3]);
        }
        float vn = dpp_sum16(nr);
        float vd = dpp_sum16(dr);
        if (tx == 15) {
            atomicAdd(&num_r[b * NN + i0 + ty + k * 16], vn);
            atomicAdd(&den_r[b * NN + i0 + ty + k * 16], vd);
        }
    }

    const int a16 = (lane ^ 16) << 2, a32 = (lane ^ 32) << 2;
#pragma unroll
    for (int l = 0; l < 8; ++l) {
        float vn = nc[l], vd = dc[l];
        vn += bperm(vn, a16); vd += bperm(vd, a16);
        vn += bperm(vn, a32); vd += bperm(vd, a32);
        if (lane < 16) { sn_w[wv][lane + l * 16] = vn; sd_w[wv][lane + l * 16] = vd; }
    }
    __syncthreads();
    if (t < TJ) {
        float ns = (sn_w[0][t] + sn_w[1][t]) + (sn_w[2][t] + sn_w[3][t]);
        float ds = (sd_w[0][t] + sd_w[1][t]) + (sd_w[2][t] + sd_w[3][t]);
        atomicAdd(&num_c[b * MM + j0 + t], ns);
        atomicAdd(&den_c[b * MM + j0 + t], ds);
    }
}

__global__ __launch_bounds__(256)
void finalize_kernel(const float* __restrict__ num_r, const float* __restrict__ den_r,
                     const float* __restrict__ num_c, const float* __restrict__ den_c,
                     float* __restrict__ out) {
    const int gid = blockIdx.x * 256 + threadIdx.x;
    float s = 0.0f;
    for (int idx = gid; idx < BB * NN; idx += 32 * 256) {
        s = fmaf(num_r[idx], __builtin_amdgcn_rcpf(den_r[idx]), s);
        s = fmaf(num_c[idx], __builtin_amdgcn_rcpf(den_c[idx]), s);
    }
#pragma unroll
    for (int m = 1; m < 64; m <<= 1) s += __shfl_xor(s, m);
    __shared__ float wsum[4];
    const int t = threadIdx.x;
    if ((t & 63) == 0) wsum[t >> 6] = s;
    __syncthreads();
    if (t == 0) {
        float v = (wsum[0] + wsum[1] + wsum[2] + wsum[3]) * (1.0f / (float)(BB * NN));
        atomicAdd(out, v);
    }
}

extern "C" void kernel_launch(void* const* d_in, const int* in_sizes, int n_in,
                              void* d_out, int out_size, void* d_ws, size_t ws_size,
                              hipStream_t stream) {
    const float* x = (const float*)d_in[0];
    const float* y = (const float*)d_in[1];
    float* ws = (float*)d_ws;

    unsigned int* m2_row = (unsigned int*)(ws);
    unsigned int* m2_col = (unsigned int*)(ws + 16384);
    float* num_r = ws + 32768;
    float* den_r = ws + 49152;
    float* num_c = ws + 65536;
    float* den_c = ws + 81920;

    hipLaunchKernelGGL(init_ws_kernel, dim3(384), dim3(256), 0, stream, ws, (float*)d_out);
    dim3 grid(BB * NTI * NTJ);  // 4096 blocks
    hipLaunchKernelGGL(pass1_min, grid, dim3(256), 0, stream, x, y, m2_row, m2_col);
    hipLaunchKernelGGL(pass2_acc, grid, dim3(256), 0, stream,
                       x, y, m2_row, m2_col, num_r, den_r, num_c, den_c);
    hipLaunchKernelGGL(finalize_kernel, dim3(32), dim3(256), 0, stream,
                       num_r, den_r, num_c, den_c, (float*)d_out);
}

// Round 14
// 63.198 us; speedup vs baseline: 1.5729x; 1.0897x over previous
//
#include <hip/hip_runtime.h>
#include <math.h>

#define BB 4
#define NN 4096
#define MM 4096
#define TI 128
#define TJ 128
#define NTI (NN / TI)   // 32
#define NTJ (MM / TJ)   // 32
#define NROW (BB * NN)  // 16384
#define NCOL (BB * MM)  // 16384

#define L2E100 144.26950408889634f   // 100*log2(e); exp(-100 d) = exp2(-L2E100 d)

// ---------- cross-lane helpers ----------
__device__ __forceinline__ float dpp_sum16(float v) {
    float t;
    t = __int_as_float(__builtin_amdgcn_update_dpp(0, __float_as_int(v), 0x111, 0xF, 0xF, true)); v += t;
    t = __int_as_float(__builtin_amdgcn_update_dpp(0, __float_as_int(v), 0x112, 0xF, 0xF, true)); v += t;
    t = __int_as_float(__builtin_amdgcn_update_dpp(0, __float_as_int(v), 0x114, 0xF, 0xF, true)); v += t;
    t = __int_as_float(__builtin_amdgcn_update_dpp(0, __float_as_int(v), 0x118, 0xF, 0xF, true)); v += t;
    return v;  // total in lane (tx==15)
}
__device__ __forceinline__ float dpp_min16(float v) {
    float t;
    t = __int_as_float(__builtin_amdgcn_update_dpp(__float_as_int(v), __float_as_int(v), 0x111, 0xF, 0xF, false)); v = fminf(v, t);
    t = __int_as_float(__builtin_amdgcn_update_dpp(__float_as_int(v), __float_as_int(v), 0x112, 0xF, 0xF, false)); v = fminf(v, t);
    t = __int_as_float(__builtin_amdgcn_update_dpp(__float_as_int(v), __float_as_int(v), 0x114, 0xF, 0xF, false)); v = fminf(v, t);
    t = __int_as_float(__builtin_amdgcn_update_dpp(__float_as_int(v), __float_as_int(v), 0x118, 0xF, 0xF, false)); v = fminf(v, t);
    return v;  // min in lane (tx==15)
}
__device__ __forceinline__ float bperm(float v, int addr) {
    return __int_as_float(__builtin_amdgcn_ds_bpermute(addr, __float_as_int(v)));
}

// ---------- staging: X=(-2x,|x|^2), Y=(y,|y|^2); d2 = X.Y + (Xw+Yw) ----------
__device__ __forceinline__ float4 stage_x(const float* p) {
    float a = p[0], b = p[1], c = p[2];
    float4 r; r.x = -2.0f * a; r.y = -2.0f * b; r.z = -2.0f * c;
    r.w = fmaf(a, a, fmaf(b, b, c * c));
    return r;
}
__device__ __forceinline__ float4 stage_y(const float* p) {
    float a = p[0], b = p[1], c = p[2];
    float4 r; r.x = a; r.y = b; r.z = c;
    r.w = fmaf(a, a, fmaf(b, b, c * c));
    return r;
}

// ---------- 4-pair asm blocks (R13, proven): "+v"-threaded, no remat ----------
__device__ __forceinline__ void p1_quad(
    float& Xx, float& Xy, float& Xz, float& Xw,
    float& YxA, float& YyA, float& YzA, float& YwA,
    float& YxB, float& YyB, float& YzB, float& YwB,
    float& YxC, float& YyC, float& YzC, float& YwC,
    float& YxD, float& YyD, float& YzD, float& YwD,
    float& rm, float& cmA, float& cmB, float& cmC, float& cmD)
{
    float pA, pB, pC, pD;
    asm("v_add_f32 %[pA], %[Xw], %[YwA]\n\t"
        "v_add_f32 %[pB], %[Xw], %[YwB]\n\t"
        "v_add_f32 %[pC], %[Xw], %[YwC]\n\t"
        "v_add_f32 %[pD], %[Xw], %[YwD]\n\t"
        "v_fmac_f32 %[pA], %[Xz], %[YzA]\n\t"
        "v_fmac_f32 %[pB], %[Xz], %[YzB]\n\t"
        "v_fmac_f32 %[pC], %[Xz], %[YzC]\n\t"
        "v_fmac_f32 %[pD], %[Xz], %[YzD]\n\t"
        "v_fmac_f32 %[pA], %[Xy], %[YyA]\n\t"
        "v_fmac_f32 %[pB], %[Xy], %[YyB]\n\t"
        "v_fmac_f32 %[pC], %[Xy], %[YyC]\n\t"
        "v_fmac_f32 %[pD], %[Xy], %[YyD]\n\t"
        "v_fmac_f32 %[pA], %[Xx], %[YxA]\n\t"
        "v_fmac_f32 %[pB], %[Xx], %[YxB]\n\t"
        "v_fmac_f32 %[pC], %[Xx], %[YxC]\n\t"
        "v_fmac_f32 %[pD], %[Xx], %[YxD]\n\t"
        "v_min_f32 %[rm], %[rm], %[pA]\n\t"
        "v_min_f32 %[cmA], %[cmA], %[pA]\n\t"
        "v_min_f32 %[rm], %[rm], %[pB]\n\t"
        "v_min_f32 %[cmB], %[cmB], %[pB]\n\t"
        "v_min_f32 %[rm], %[rm], %[pC]\n\t"
        "v_min_f32 %[cmC], %[cmC], %[pC]\n\t"
        "v_min_f32 %[rm], %[rm], %[pD]\n\t"
        "v_min_f32 %[cmD], %[cmD], %[pD]"
        : [pA]"=&v"(pA), [pB]"=&v"(pB), [pC]"=&v"(pC), [pD]"=&v"(pD),
          [rm]"+v"(rm), [cmA]"+v"(cmA), [cmB]"+v"(cmB), [cmC]"+v"(cmC), [cmD]"+v"(cmD),
          [Xx]"+v"(Xx), [Xy]"+v"(Xy), [Xz]"+v"(Xz), [Xw]"+v"(Xw),
          [YxA]"+v"(YxA), [YyA]"+v"(YyA), [YzA]"+v"(YzA), [YwA]"+v"(YwA),
          [YxB]"+v"(YxB), [YyB]"+v"(YyB), [YzB]"+v"(YzB), [YwB]"+v"(YwB),
          [YxC]"+v"(YxC), [YyC]"+v"(YyC), [YzC]"+v"(YzC), [YwC]"+v"(YwC),
          [YxD]"+v"(YxD), [YyD]"+v"(YyD), [YzD]"+v"(YzD), [YwD]"+v"(YwD));
}

__device__ __forceinline__ void p2_quad(
    float& Xx, float& Xy, float& Xz, float& Xw, float& sr,
    float& YxA, float& YyA, float& YzA, float& YwA, float& scA,
    float& YxB, float& YyB, float& YzB, float& YwB, float& scB,
    float& YxC, float& YyC, float& YzC, float& YwC, float& scC,
    float& YxD, float& YyD, float& YzD, float& YwD, float& scD,
    float nL,
    float& nr, float& dr,
    float& ncA, float& dcA, float& ncB, float& dcB,
    float& ncC, float& dcC, float& ncD, float& dcD)
{
    float pA, pB, pC, pD, eA, eB, eC, eD;
    asm("v_add_f32 %[pA], %[Xw], %[YwA]\n\t"
        "v_add_f32 %[pB], %[Xw], %[YwB]\n\t"
        "v_add_f32 %[pC], %[Xw], %[YwC]\n\t"
        "v_add_f32 %[pD], %[Xw], %[YwD]\n\t"
        "v_fmac_f32 %[pA], %[Xz], %[YzA]\n\t"
        "v_fmac_f32 %[pB], %[Xz], %[YzB]\n\t"
        "v_fmac_f32 %[pC], %[Xz], %[YzC]\n\t"
        "v_fmac_f32 %[pD], %[Xz], %[YzD]\n\t"
        "v_fmac_f32 %[pA], %[Xy], %[YyA]\n\t"
        "v_fmac_f32 %[pB], %[Xy], %[YyB]\n\t"
        "v_fmac_f32 %[pC], %[Xy], %[YyC]\n\t"
        "v_fmac_f32 %[pD], %[Xy], %[YyD]\n\t"
        "v_fmac_f32 %[pA], %[Xx], %[YxA]\n\t"
        "v_fmac_f32 %[pB], %[Xx], %[YxB]\n\t"
        "v_fmac_f32 %[pC], %[Xx], %[YxC]\n\t"
        "v_fmac_f32 %[pD], %[Xx], %[YxD]\n\t"
        "v_max_f32 %[pA], 0, %[pA]\n\t"
        "v_max_f32 %[pB], 0, %[pB]\n\t"
        "v_max_f32 %[pC], 0, %[pC]\n\t"
        "v_max_f32 %[pD], 0, %[pD]\n\t"
        "v_sqrt_f32 %[pA], %[pA]\n\t"
        "v_sqrt_f32 %[pB], %[pB]\n\t"
        "v_sqrt_f32 %[pC], %[pC]\n\t"
        "v_sqrt_f32 %[pD], %[pD]\n\t"
        "v_fma_f32 %[eA], %[pA], %[nL], %[sr]\n\t"
        "v_fma_f32 %[eB], %[pB], %[nL], %[sr]\n\t"
        "v_fma_f32 %[eC], %[pC], %[nL], %[sr]\n\t"
        "v_fma_f32 %[eD], %[pD], %[nL], %[sr]\n\t"
        "v_exp_f32 %[eA], %[eA]\n\t"
        "v_exp_f32 %[eB], %[eB]\n\t"
        "v_exp_f32 %[eC], %[eC]\n\t"
        "v_exp_f32 %[eD], %[eD]\n\t"
        "v_fmac_f32 %[nr], %[pA], %[eA]\n\t"
        "v_add_f32 %[dr], %[dr], %[eA]\n\t"
        "v_fma_f32 %[eA], %[pA], %[nL], %[scA]\n\t"
        "v_fmac_f32 %[nr], %[pB], %[eB]\n\t"
        "v_add_f32 %[dr], %[dr], %[eB]\n\t"
        "v_fma_f32 %[eB], %[pB], %[nL], %[scB]\n\t"
        "v_fmac_f32 %[nr], %[pC], %[eC]\n\t"
        "v_add_f32 %[dr], %[dr], %[eC]\n\t"
        "v_fma_f32 %[eC], %[pC], %[nL], %[scC]\n\t"
        "v_fmac_f32 %[nr], %[pD], %[eD]\n\t"
        "v_add_f32 %[dr], %[dr], %[eD]\n\t"
        "v_fma_f32 %[eD], %[pD], %[nL], %[scD]\n\t"
        "v_exp_f32 %[eA], %[eA]\n\t"
        "v_exp_f32 %[eB], %[eB]\n\t"
        "v_exp_f32 %[eC], %[eC]\n\t"
        "v_exp_f32 %[eD], %[eD]\n\t"
        "v_fmac_f32 %[ncA], %[pA], %[eA]\n\t"
        "v_add_f32 %[dcA], %[dcA], %[eA]\n\t"
        "v_fmac_f32 %[ncB], %[pB], %[eB]\n\t"
        "v_add_f32 %[dcB], %[dcB], %[eB]\n\t"
        "v_fmac_f32 %[ncC], %[pC], %[eC]\n\t"
        "v_add_f32 %[dcC], %[dcC], %[eC]\n\t"
        "v_fmac_f32 %[ncD], %[pD], %[eD]\n\t"
        "v_add_f32 %[dcD], %[dcD], %[eD]"
        : [pA]"=&v"(pA), [pB]"=&v"(pB), [pC]"=&v"(pC), [pD]"=&v"(pD),
          [eA]"=&v"(eA), [eB]"=&v"(eB), [eC]"=&v"(eC), [eD]"=&v"(eD),
          [nr]"+v"(nr), [dr]"+v"(dr),
          [ncA]"+v"(ncA), [dcA]"+v"(dcA), [ncB]"+v"(ncB), [dcB]"+v"(dcB),
          [ncC]"+v"(ncC), [dcC]"+v"(dcC), [ncD]"+v"(ncD), [dcD]"+v"(dcD),
          [Xx]"+v"(Xx), [Xy]"+v"(Xy), [Xz]"+v"(Xz), [Xw]"+v"(Xw), [sr]"+v"(sr),
          [YxA]"+v"(YxA), [YyA]"+v"(YyA), [YzA]"+v"(YzA), [YwA]"+v"(YwA), [scA]"+v"(scA),
          [YxB]"+v"(YxB), [YyB]"+v"(YyB), [YzB]"+v"(YzB), [YwB]"+v"(YwB), [scB]"+v"(scB),
          [YxC]"+v"(YxC), [YyC]"+v"(YyC), [YzC]"+v"(YzC), [YwC]"+v"(YwC), [scC]"+v"(scC),
          [YxD]"+v"(YxD), [YyD]"+v"(YyD), [YzD]"+v"(YzD), [YwD]"+v"(YwD), [scD]"+v"(scD)
        : [nL]"s"(nL));
}

// ================= MERGED PATH (needs ~12.6MB ws) =================
// Block-local shifts: per (row, col-block) partial (s_b, num_b, den_b),
// non-atomic writes. Finalize rebases: x exp2(s_g - s_b), s_g = min_b s_b
// (factor <= 1, no overflow; den_g >= 1 since min block contributes exp2(0)).
// Eliminates pass1, init, and all global atomics.

__global__ __launch_bounds__(256)
void merged_pass(const float* __restrict__ x, const float* __restrict__ y,
                 float* __restrict__ sR, float* __restrict__ numR, float* __restrict__ denR,
                 float* __restrict__ sC, float* __restrict__ numC, float* __restrict__ denC) {
    const int bid = blockIdx.x;
    const int b   = bid / (NTI * NTJ);
    const int rem = bid % (NTI * NTJ);
    const int ib  = rem / NTJ, jb = rem % NTJ;
    const int i0  = ib * TI, j0 = jb * TJ;

    __shared__ float4 xs4[TI];
    __shared__ float4 ys4[TJ];
    __shared__ float  ar[TI], ac[TJ], rowmin_s[TI];
    __shared__ float  cm_w[4][TJ];
    __shared__ float  sn_w[4][TJ], sd_w[4][TJ];

    const int t = threadIdx.x;
    if (t < TI) xs4[t] = stage_x(&x[(size_t)(b * NN + i0 + t) * 3]);
    else        ys4[t - TI] = stage_y(&y[(size_t)(b * MM + j0 + (t - TI)) * 3]);
    __syncthreads();

    const int tx = t & 15, ty = t >> 4;
    const int lane = t & 63, wv = t >> 6;
    const int a16 = (lane ^ 16) << 2, a32 = (lane ^ 32) << 2;

    float Yx[8], Yy[8], Yz[8], Yw[8], cmin[8];
#pragma unroll
    for (int l = 0; l < 8; ++l) {
        float4 v = ys4[tx + l * 16];
        Yx[l] = v.x; Yy[l] = v.y; Yz[l] = v.z; Yw[l] = v.w;
        cmin[l] = 1e30f;
    }

    // ---- micro-pass A: block-local row/col mins ----
#pragma unroll
    for (int k = 0; k < 8; ++k) {
        float4 Xv = xs4[ty + k * 16];
        float Xx = Xv.x, Xy = Xv.y, Xz = Xv.z, Xw = Xv.w;
        float rmin = 1e30f;
#pragma unroll
        for (int l = 0; l < 8; l += 4) {
            p1_quad(Xx, Xy, Xz, Xw,
                    Yx[l], Yy[l], Yz[l], Yw[l],
                    Yx[l+1], Yy[l+1], Yz[l+1], Yw[l+1],
                    Yx[l+2], Yy[l+2], Yz[l+2], Yw[l+2],
                    Yx[l+3], Yy[l+3], Yz[l+3], Yw[l+3],
                    rmin, cmin[l], cmin[l+1], cmin[l+2], cmin[l+3]);
        }
        rmin = dpp_min16(rmin);
        if (tx == 15) rowmin_s[ty + k * 16] = rmin;   // each row owned by one wave
    }
#pragma unroll
    for (int l = 0; l < 8; ++l) {
        float v = cmin[l];
        v = fminf(v, bperm(v, a16));
        v = fminf(v, bperm(v, a32));
        if (lane < 16) cm_w[wv][lane + l * 16] = v;
    }
    __syncthreads();

    // ---- local shifts + write s partials ----
    if (t < TI) {
        float s = L2E100 * __builtin_amdgcn_sqrtf(fmaxf(rowmin_s[t], 0.0f));
        ar[t] = s;
        sR[(size_t)jb * NROW + b * NN + i0 + t] = s;
    } else {
        int j = t - TI;
        float m = fminf(fminf(cm_w[0][j], cm_w[1][j]), fminf(cm_w[2][j], cm_w[3][j]));
        float s = L2E100 * __builtin_amdgcn_sqrtf(fmaxf(m, 0.0f));
        ac[j] = s;
        sC[(size_t)ib * NCOL + b * MM + j0 + j] = s;
    }
    __syncthreads();

    // ---- micro-pass B: weighted sums with local shifts ----
    const float nL = -L2E100;
    float sc[8], nc[8], dc[8];
#pragma unroll
    for (int l = 0; l < 8; ++l) { sc[l] = ac[tx + l * 16]; nc[l] = 0.0f; dc[l] = 0.0f; }

#pragma unroll
    for (int k = 0; k < 8; ++k) {
        float4 Xv = xs4[ty + k * 16];
        float Xx = Xv.x, Xy = Xv.y, Xz = Xv.z, Xw = Xv.w;
        float srk = ar[ty + k * 16];
        float nr = 0.0f, dr = 0.0f;
#pragma unroll
        for (int l = 0; l < 8; l += 4) {
            p2_quad(Xx, Xy, Xz, Xw, srk,
                    Yx[l], Yy[l], Yz[l], Yw[l], sc[l],
                    Yx[l+1], Yy[l+1], Yz[l+1], Yw[l+1], sc[l+1],
                    Yx[l+2], Yy[l+2], Yz[l+2], Yw[l+2], sc[l+2],
                    Yx[l+3], Yy[l+3], Yz[l+3], Yw[l+3], sc[l+3],
                    nL, nr, dr,
                    nc[l], dc[l], nc[l+1], dc[l+1],
                    nc[l+2], dc[l+2], nc[l+3], dc[l+3]);
        }
        float vn = dpp_sum16(nr);
        float vd = dpp_sum16(dr);
        if (tx == 15) {
            size_t idx = (size_t)jb * NROW + b * NN + i0 + ty + k * 16;
            numR[idx] = vn;            // non-atomic: one writer per (row, jb)
            denR[idx] = vd;
        }
    }

#pragma unroll
    for (int l = 0; l < 8; ++l) {
        float vn = nc[l], vd = dc[l];
        vn += bperm(vn, a16); vd += bperm(vd, a16);
        vn += bperm(vn, a32); vd += bperm(vd, a32);
        if (lane < 16) { sn_w[wv][lane + l * 16] = vn; sd_w[wv][lane + l * 16] = vd; }
    }
    __syncthreads();
    if (t < TJ) {
        size_t idx = (size_t)ib * NCOL + b * MM + j0 + t;
        numC[idx] = (sn_w[0][t] + sn_w[1][t]) + (sn_w[2][t] + sn_w[3][t]);
        denC[idx] = (sd_w[0][t] + sd_w[1][t]) + (sd_w[2][t] + sd_w[3][t]);
    }
}

__global__ __launch_bounds__(256)
void finalize2(const float* __restrict__ sR, const float* __restrict__ numR, const float* __restrict__ denR,
               const float* __restrict__ sC, const float* __restrict__ numC, const float* __restrict__ denC,
               float* __restrict__ bsum) {
    const int gid = blockIdx.x * 256 + threadIdx.x;   // 0..32767
    const float* S; const float* NU; const float* DE; int idx;
    if (gid < NROW) { S = sR; NU = numR; DE = denR; idx = gid; }
    else            { S = sC; NU = numC; DE = denC; idx = gid - NROW; }

    float m = 1e30f;
#pragma unroll 4
    for (int pb = 0; pb < 32; ++pb) m = fminf(m, S[(size_t)pb * NROW + idx]);
    float nu = 0.0f, de = 0.0f;
#pragma unroll 4
    for (int pb = 0; pb < 32; ++pb) {
        size_t o = (size_t)pb * NROW + idx;
        float f = __builtin_amdgcn_exp2f(m - S[o]);   // <= 0 arg: no overflow
        nu = fmaf(NU[o], f, nu);
        de = fmaf(DE[o], f, de);
    }
    float q = nu * __builtin_amdgcn_rcpf(de);         // de >= 1

#pragma unroll
    for (int s = 1; s < 64; s <<= 1) q += __shfl_xor(q, s);
    __shared__ float wsum[4];
    const int t = threadIdx.x;
    if ((t & 63) == 0) wsum[t >> 6] = q;
    __syncthreads();
    if (t == 0) bsum[blockIdx.x] = (wsum[0] + wsum[1]) + (wsum[2] + wsum[3]);
}

__global__ __launch_bounds__(256)
void final_sum(const float* __restrict__ bsum, float* __restrict__ out) {
    const int t = threadIdx.x;
    float s = (t < 128) ? bsum[t] : 0.0f;
#pragma unroll
    for (int m = 1; m < 64; m <<= 1) s += __shfl_xor(s, m);
    __shared__ float wsum[4];
    if ((t & 63) == 0) wsum[t >> 6] = s;
    __syncthreads();
    if (t == 0) out[0] = (wsum[0] + wsum[1] + wsum[2] + wsum[3]) * (1.0f / (float)(BB * NN));
}

// ================= FALLBACK PATH (R13, 384KB ws) =================
__global__ __launch_bounds__(256)
void init_ws_kernel(float* ws, float* out) {
    int idx = blockIdx.x * 256 + threadIdx.x;
    if (idx < 2 * 16384) ws[idx] = 1e30f;
    else if (idx < 6 * 16384) ws[idx] = 0.0f;
    if (idx == 0) out[0] = 0.0f;
}

__global__ __launch_bounds__(256)
void pass1_min(const float* __restrict__ x, const float* __restrict__ y,
               unsigned int* __restrict__ m2_row, unsigned int* __restrict__ m2_col) {
    const int bid = blockIdx.x;
    const int b   = bid / (NTI * NTJ);
    const int rem = bid % (NTI * NTJ);
    const int i0  = (rem / NTJ) * TI;
    const int j0  = (rem % NTJ) * TJ;

    __shared__ float4 xs4[TI];
    __shared__ float4 ys4[TJ];
    __shared__ float  cm_w[4][TJ];

    const int t = threadIdx.x;
    if (t < TI) xs4[t] = stage_x(&x[(size_t)(b * NN + i0 + t) * 3]);
    else        ys4[t - TI] = stage_y(&y[(size_t)(b * MM + j0 + (t - TI)) * 3]);
    __syncthreads();

    const int tx = t & 15, ty = t >> 4;
    const int lane = t & 63, wv = t >> 6;
    float Yx[8], Yy[8], Yz[8], Yw[8], cmin[8];
#pragma unroll
    for (int l = 0; l < 8; ++l) {
        float4 v = ys4[tx + l * 16];
        Yx[l] = v.x; Yy[l] = v.y; Yz[l] = v.z; Yw[l] = v.w;
        cmin[l] = 1e30f;
    }
#pragma unroll
    for (int k = 0; k < 8; ++k) {
        float4 Xv = xs4[ty + k * 16];
        float Xx = Xv.x, Xy = Xv.y, Xz = Xv.z, Xw = Xv.w;
        float rmin = 1e30f;
#pragma unroll
        for (int l = 0; l < 8; l += 4) {
            p1_quad(Xx, Xy, Xz, Xw,
                    Yx[l], Yy[l], Yz[l], Yw[l],
                    Yx[l+1], Yy[l+1], Yz[l+1], Yw[l+1],
                    Yx[l+2], Yy[l+2], Yz[l+2], Yw[l+2],
                    Yx[l+3], Yy[l+3], Yz[l+3], Yw[l+3],
                    rmin, cmin[l], cmin[l+1], cmin[l+2], cmin[l+3]);
        }
        rmin = dpp_min16(rmin);
        if (tx == 15) atomicMin(&m2_row[b * NN + i0 + ty + k * 16], __float_as_uint(rmin));
    }
    const int a16 = (lane ^ 16) << 2, a32 = (lane ^ 32) << 2;
#pragma unroll
    for (int l = 0; l < 8; ++l) {
        float v = cmin[l];
        v = fminf(v, bperm(v, a16));
        v = fminf(v, bperm(v, a32));
        if (lane < 16) cm_w[wv][lane + l * 16] = v;
    }
    __syncthreads();
    if (t < TJ) {
        float m = fminf(fminf(cm_w[0][t], cm_w[1][t]), fminf(cm_w[2][t], cm_w[3][t]));
        atomicMin(&m2_col[b * MM + j0 + t], __float_as_uint(m));
    }
}

__global__ __launch_bounds__(256)
void pass2_acc(const float* __restrict__ x, const float* __restrict__ y,
               const unsigned int* __restrict__ m2_row, const unsigned int* __restrict__ m2_col,
               float* __restrict__ num_r, float* __restrict__ den_r,
               float* __restrict__ num_c, float* __restrict__ den_c) {
    const int bid = blockIdx.x;
    const int b   = bid / (NTI * NTJ);
    const int rem = bid % (NTI * NTJ);
    const int i0  = (rem / NTJ) * TI;
    const int j0  = (rem % NTJ) * TJ;

    __shared__ float4 xs4[TI];
    __shared__ float4 ys4[TJ];
    __shared__ float  ar[TI];
    __shared__ float  ac[TJ];
    __shared__ float  sn_w[4][TJ];
    __shared__ float  sd_w[4][TJ];

    const int t = threadIdx.x;
    if (t < TI) {
        xs4[t] = stage_x(&x[(size_t)(b * NN + i0 + t) * 3]);
        ar[t]  = L2E100 * __builtin_amdgcn_sqrtf(fmaxf(__uint_as_float(m2_row[b * NN + i0 + t]), 0.0f));
    } else {
        int j = t - TI;
        ys4[j] = stage_y(&y[(size_t)(b * MM + j0 + j) * 3]);
        ac[j]  = L2E100 * __builtin_amdgcn_sqrtf(fmaxf(__uint_as_float(m2_col[b * MM + j0 + j]), 0.0f));
    }
    __syncthreads();

    const int tx = t & 15, ty = t >> 4;
    const int lane = t & 63, wv = t >> 6;
    const float nL = -L2E100;

    float Yx[8], Yy[8], Yz[8], Yw[8], sc[8], nc[8], dc[8];
#pragma unroll
    for (int l = 0; l < 8; ++l) {
        float4 v = ys4[tx + l * 16];
        Yx[l] = v.x; Yy[l] = v.y; Yz[l] = v.z; Yw[l] = v.w;
        sc[l] = ac[tx + l * 16];
        nc[l] = 0.0f; dc[l] = 0.0f;
    }
#pragma unroll
    for (int k = 0; k < 8; ++k) {
        float4 Xv = xs4[ty + k * 16];
        float Xx = Xv.x, Xy = Xv.y, Xz = Xv.z, Xw = Xv.w;
        float srk = ar[ty + k * 16];
        float nr = 0.0f, dr = 0.0f;
#pragma unroll
        for (int l = 0; l < 8; l += 4) {
            p2_quad(Xx, Xy, Xz, Xw, srk,
                    Yx[l], Yy[l], Yz[l], Yw[l], sc[l],
                    Yx[l+1], Yy[l+1], Yz[l+1], Yw[l+1], sc[l+1],
                    Yx[l+2], Yy[l+2], Yz[l+2], Yw[l+2], sc[l+2],
                    Yx[l+3], Yy[l+3], Yz[l+3], Yw[l+3], sc[l+3],
                    nL, nr, dr,
                    nc[l], dc[l], nc[l+1], dc[l+1],
                    nc[l+2], dc[l+2], nc[l+3], dc[l+3]);
        }
        float vn = dpp_sum16(nr);
        float vd = dpp_sum16(dr);
        if (tx == 15) {
            atomicAdd(&num_r[b * NN + i0 + ty + k * 16], vn);
            atomicAdd(&den_r[b * NN + i0 + ty + k * 16], vd);
        }
    }
    const int a16 = (lane ^ 16) << 2, a32 = (lane ^ 32) << 2;
#pragma unroll
    for (int l = 0; l < 8; ++l) {
        float vn = nc[l], vd = dc[l];
        vn += bperm(vn, a16); vd += bperm(vd, a16);
        vn += bperm(vn, a32); vd += bperm(vd, a32);
        if (lane < 16) { sn_w[wv][lane + l * 16] = vn; sd_w[wv][lane + l * 16] = vd; }
    }
    __syncthreads();
    if (t < TJ) {
        float ns = (sn_w[0][t] + sn_w[1][t]) + (sn_w[2][t] + sn_w[3][t]);
        float ds = (sd_w[0][t] + sd_w[1][t]) + (sd_w[2][t] + sd_w[3][t]);
        atomicAdd(&num_c[b * MM + j0 + t], ns);
        atomicAdd(&den_c[b * MM + j0 + t], ds);
    }
}

__global__ __launch_bounds__(256)
void finalize_kernel(const float* __restrict__ num_r, const float* __restrict__ den_r,
                     const float* __restrict__ num_c, const float* __restrict__ den_c,
                     float* __restrict__ out) {
    const int gid = blockIdx.x * 256 + threadIdx.x;
    float s = 0.0f;
    for (int idx = gid; idx < BB * NN; idx += 32 * 256) {
        s = fmaf(num_r[idx], __builtin_amdgcn_rcpf(den_r[idx]), s);
        s = fmaf(num_c[idx], __builtin_amdgcn_rcpf(den_c[idx]), s);
    }
#pragma unroll
    for (int m = 1; m < 64; m <<= 1) s += __shfl_xor(s, m);
    __shared__ float wsum[4];
    const int t = threadIdx.x;
    if ((t & 63) == 0) wsum[t >> 6] = s;
    __syncthreads();
    if (t == 0) {
        float v = (wsum[0] + wsum[1] + wsum[2] + wsum[3]) * (1.0f / (float)(BB * NN));
        atomicAdd(out, v);
    }
}

extern "C" void kernel_launch(void* const* d_in, const int* in_sizes, int n_in,
                              void* d_out, int out_size, void* d_ws, size_t ws_size,
                              hipStream_t stream) {
    const float* x = (const float*)d_in[0];
    const float* y = (const float*)d_in[1];
    float* ws = (float*)d_ws;

    const size_t PART = (size_t)32 * NROW;      // 524288 floats per partial array
    const size_t need = (6 * PART + 256) * sizeof(float);  // ~12.6MB

    if (ws_size >= need) {
        // merged path: no init, no pass1, no atomics
        float* sR   = ws;
        float* numR = ws + PART;
        float* denR = ws + 2 * PART;
        float* sC   = ws + 3 * PART;
        float* numC = ws + 4 * PART;
        float* denC = ws + 5 * PART;
        float* bsum = ws + 6 * PART;

        hipLaunchKernelGGL(merged_pass, dim3(BB * NTI * NTJ), dim3(256), 0, stream,
                           x, y, sR, numR, denR, sC, numC, denC);
        hipLaunchKernelGGL(finalize2, dim3(128), dim3(256), 0, stream,
                           sR, numR, denR, sC, numC, denC, bsum);
        hipLaunchKernelGGL(final_sum, dim3(1), dim3(256), 0, stream, bsum, (float*)d_out);
    } else {
        // fallback: R13 3-kernel path (384KB ws)
        unsigned int* m2_row = (unsigned int*)(ws);
        unsigned int* m2_col = (unsigned int*)(ws + 16384);
        float* num_r = ws + 32768;
        float* den_r = ws + 49152;
        float* num_c = ws + 65536;
        float* den_c = ws + 81920;

        hipLaunchKernelGGL(init_ws_kernel, dim3(384), dim3(256), 0, stream, ws, (float*)d_out);
        dim3 grid(BB * NTI * NTJ);
        hipLaunchKernelGGL(pass1_min, grid, dim3(256), 0, stream, x, y, m2_row, m2_col);
        hipLaunchKernelGGL(pass2_acc, grid, dim3(256), 0, stream,
                           x, y, m2_row, m2_col, num_r, den_r, num_c, den_c);
        hipLaunchKernelGGL(finalize_kernel, dim3(32), dim3(256), 0, stream,
                           num_r, den_r, num_c, den_c, (float*)d_out);
    }
}

// Round 15
// 63.164 us; speedup vs baseline: 1.5737x; 1.0005x over previous
//
#include <hip/hip_runtime.h>
#include <math.h>

#define BB 4
#define NN 4096
#define MM 4096
#define TI 128
#define TJ 128
#define NTI (NN / TI)   // 32
#define NTJ (MM / TJ)   // 32
#define NROW (BB * NN)  // 16384
#define NCOL (BB * MM)  // 16384

#define L2E100 144.26950408889634f   // 100*log2(e); exp(-100 d) = exp2(-L2E100 d)

typedef __attribute__((ext_vector_type(2))) float f32x2;

// ---------- cross-lane helpers ----------
__device__ __forceinline__ float dpp_sum16(float v) {
    float t;
    t = __int_as_float(__builtin_amdgcn_update_dpp(0, __float_as_int(v), 0x111, 0xF, 0xF, true)); v += t;
    t = __int_as_float(__builtin_amdgcn_update_dpp(0, __float_as_int(v), 0x112, 0xF, 0xF, true)); v += t;
    t = __int_as_float(__builtin_amdgcn_update_dpp(0, __float_as_int(v), 0x114, 0xF, 0xF, true)); v += t;
    t = __int_as_float(__builtin_amdgcn_update_dpp(0, __float_as_int(v), 0x118, 0xF, 0xF, true)); v += t;
    return v;  // total in lane (tx==15)
}
__device__ __forceinline__ float dpp_min16(float v) {
    float t;
    t = __int_as_float(__builtin_amdgcn_update_dpp(__float_as_int(v), __float_as_int(v), 0x111, 0xF, 0xF, false)); v = fminf(v, t);
    t = __int_as_float(__builtin_amdgcn_update_dpp(__float_as_int(v), __float_as_int(v), 0x112, 0xF, 0xF, false)); v = fminf(v, t);
    t = __int_as_float(__builtin_amdgcn_update_dpp(__float_as_int(v), __float_as_int(v), 0x114, 0xF, 0xF, false)); v = fminf(v, t);
    t = __int_as_float(__builtin_amdgcn_update_dpp(__float_as_int(v), __float_as_int(v), 0x118, 0xF, 0xF, false)); v = fminf(v, t);
    return v;  // min in lane (tx==15)
}
__device__ __forceinline__ float bperm(float v, int addr) {
    return __int_as_float(__builtin_amdgcn_ds_bpermute(addr, __float_as_int(v)));
}

// ---------- packed helpers ----------
__device__ __forceinline__ f32x2 vmin2(f32x2 a, f32x2 b) {
    f32x2 r; r.x = fminf(a.x, b.x); r.y = fminf(a.y, b.y); return r;
}
__device__ __forceinline__ f32x2 vmax0(f32x2 a) {
    f32x2 r; r.x = fmaxf(a.x, 0.0f); r.y = fmaxf(a.y, 0.0f); return r;
}
__device__ __forceinline__ f32x2 vsqrt2(f32x2 a) {
    f32x2 r; r.x = __builtin_amdgcn_sqrtf(a.x); r.y = __builtin_amdgcn_sqrtf(a.y); return r;
}
__device__ __forceinline__ f32x2 vexp2(f32x2 a) {
    f32x2 r; r.x = __builtin_amdgcn_exp2f(a.x); r.y = __builtin_amdgcn_exp2f(a.y); return r;
}
// SHARED packed d2: used by BOTH micro-passes -> bitwise-identical d2, so the
// block-local shift satisfies sr <= L*d exactly (exp2 arg <= 0, no overflow).
// -ffp-contract=fast (HIP default) fuses a*b+c into v_pk_fma_f32 (full-rate
// dual FP32 on CDNA2+).
__device__ __forceinline__ f32x2 pair_d2_pk(f32x2 Xx2, f32x2 Xy2, f32x2 Xz2, f32x2 Xw2,
                                            f32x2 Yx2, f32x2 Yy2, f32x2 Yz2, f32x2 Yw2) {
    f32x2 pq = Xw2 + Yw2;
    pq = Xz2 * Yz2 + pq;
    pq = Xy2 * Yy2 + pq;
    pq = Xx2 * Yx2 + pq;
    return pq;
}

// ---------- staging: X=(-2x,|x|^2), Y=(y,|y|^2); d2 = X.Y + (Xw+Yw) ----------
__device__ __forceinline__ float4 stage_x(const float* p) {
    float a = p[0], b = p[1], c = p[2];
    float4 r; r.x = -2.0f * a; r.y = -2.0f * b; r.z = -2.0f * c;
    r.w = fmaf(a, a, fmaf(b, b, c * c));
    return r;
}
__device__ __forceinline__ float4 stage_y(const float* p) {
    float a = p[0], b = p[1], c = p[2];
    float4 r; r.x = a; r.y = b; r.z = c;
    r.w = fmaf(a, a, fmaf(b, b, c * c));
    return r;
}

// ================= MERGED PATH (needs ~12.6MB ws) =================
// Block-local shifts; per (row, col-block) partials (s,num,den); non-atomic.
// finalize2 rebases with exp2(s_g - s_b) <= 1 and combines.

__global__ __launch_bounds__(256)
void merged_pass(const float* __restrict__ x, const float* __restrict__ y,
                 float* __restrict__ sR, float* __restrict__ numR, float* __restrict__ denR,
                 float* __restrict__ sC, float* __restrict__ numC, float* __restrict__ denC) {
    const int bid = blockIdx.x;
    const int b   = bid / (NTI * NTJ);
    const int rem = bid % (NTI * NTJ);
    const int ib  = rem / NTJ, jb = rem % NTJ;
    const int i0  = ib * TI, j0 = jb * TJ;

    __shared__ float4 xs4[TI];
    __shared__ float4 ys4[TJ];
    __shared__ float  ar[TI], ac[TJ], rowmin_s[TI];
    __shared__ float  cm_w[4][TJ];
    __shared__ float  sn_w[4][TJ], sd_w[4][TJ];

    const int t = threadIdx.x;
    if (t < TI) xs4[t] = stage_x(&x[(size_t)(b * NN + i0 + t) * 3]);
    else        ys4[t - TI] = stage_y(&y[(size_t)(b * MM + j0 + (t - TI)) * 3]);
    __syncthreads();

    const int tx = t & 15, ty = t >> 4;
    const int lane = t & 63, wv = t >> 6;
    const int a16 = (lane ^ 16) << 2, a32 = (lane ^ 32) << 2;

    // packed Y fragments: pair p holds cols (2p, 2p+1)
    f32x2 Yx2[4], Yy2[4], Yz2[4], Yw2[4], cm2[4];
#pragma unroll
    for (int p = 0; p < 4; ++p) {
        float4 a = ys4[tx + (2 * p) * 16];
        float4 c = ys4[tx + (2 * p + 1) * 16];
        Yx2[p] = (f32x2){a.x, c.x}; Yy2[p] = (f32x2){a.y, c.y};
        Yz2[p] = (f32x2){a.z, c.z}; Yw2[p] = (f32x2){a.w, c.w};
        cm2[p] = (f32x2){1e30f, 1e30f};
    }

    // ---- micro-pass A: block-local row/col mins (packed) ----
#pragma unroll
    for (int k = 0; k < 8; ++k) {
        float4 Xv = xs4[ty + k * 16];
        f32x2 Xx2 = (f32x2){Xv.x, Xv.x}, Xy2 = (f32x2){Xv.y, Xv.y};
        f32x2 Xz2 = (f32x2){Xv.z, Xv.z}, Xw2 = (f32x2){Xv.w, Xv.w};
        f32x2 rm2 = (f32x2){1e30f, 1e30f};
#pragma unroll
        for (int p = 0; p < 4; ++p) {
            f32x2 pq = pair_d2_pk(Xx2, Xy2, Xz2, Xw2, Yx2[p], Yy2[p], Yz2[p], Yw2[p]);
            rm2 = vmin2(rm2, pq);
            cm2[p] = vmin2(cm2[p], pq);
        }
        float rmin = dpp_min16(fminf(rm2.x, rm2.y));
        if (tx == 15) rowmin_s[ty + k * 16] = rmin;   // row owned by one wave
    }
#pragma unroll
    for (int p = 0; p < 4; ++p) {
#pragma unroll
        for (int h = 0; h < 2; ++h) {
            float v = h ? cm2[p].y : cm2[p].x;
            v = fminf(v, bperm(v, a16));
            v = fminf(v, bperm(v, a32));
            if (lane < 16) cm_w[wv][lane + (2 * p + h) * 16] = v;
        }
    }
    __syncthreads();

    // ---- local shifts + write s partials ----
    if (t < TI) {
        float s = L2E100 * __builtin_amdgcn_sqrtf(fmaxf(rowmin_s[t], 0.0f));
        ar[t] = s;
        sR[(size_t)jb * NROW + b * NN + i0 + t] = s;
    } else {
        int j = t - TI;
        float m = fminf(fminf(cm_w[0][j], cm_w[1][j]), fminf(cm_w[2][j], cm_w[3][j]));
        float s = L2E100 * __builtin_amdgcn_sqrtf(fmaxf(m, 0.0f));
        ac[j] = s;
        sC[(size_t)ib * NCOL + b * MM + j0 + j] = s;
    }
    __syncthreads();

    // ---- micro-pass B: packed weighted sums with local shifts ----
    const f32x2 nL2 = (f32x2){-L2E100, -L2E100};
    f32x2 sc2[4], nc2[4], dc2[4];
#pragma unroll
    for (int p = 0; p < 4; ++p) {
        sc2[p] = (f32x2){ac[tx + (2 * p) * 16], ac[tx + (2 * p + 1) * 16]};
        nc2[p] = (f32x2){0.0f, 0.0f}; dc2[p] = (f32x2){0.0f, 0.0f};
    }

#pragma unroll
    for (int k = 0; k < 8; ++k) {
        float4 Xv = xs4[ty + k * 16];
        f32x2 Xx2 = (f32x2){Xv.x, Xv.x}, Xy2 = (f32x2){Xv.y, Xv.y};
        f32x2 Xz2 = (f32x2){Xv.z, Xv.z}, Xw2 = (f32x2){Xv.w, Xv.w};
        float srk = ar[ty + k * 16];
        f32x2 sr2 = (f32x2){srk, srk};
        f32x2 nr2 = (f32x2){0.0f, 0.0f}, dr2 = (f32x2){0.0f, 0.0f};
#pragma unroll
        for (int p = 0; p < 4; ++p) {
            f32x2 pq = pair_d2_pk(Xx2, Xy2, Xz2, Xw2, Yx2[p], Yy2[p], Yz2[p], Yw2[p]);
            f32x2 d  = vsqrt2(vmax0(pq));
            f32x2 eR = vexp2(d * nL2 + sr2);     // arg <= 0
            nr2 = d * eR + nr2;
            dr2 = dr2 + eR;
            f32x2 eC = vexp2(d * nL2 + sc2[p]);  // arg <= 0
            nc2[p] = d * eC + nc2[p];
            dc2[p] = dc2[p] + eC;
        }
        float vn = dpp_sum16(nr2.x + nr2.y);
        float vd = dpp_sum16(dr2.x + dr2.y);
        if (tx == 15) {
            size_t idx = (size_t)jb * NROW + b * NN + i0 + ty + k * 16;
            numR[idx] = vn;            // one writer per (row, jb)
            denR[idx] = vd;
        }
    }

#pragma unroll
    for (int p = 0; p < 4; ++p) {
#pragma unroll
        for (int h = 0; h < 2; ++h) {
            float vn = h ? nc2[p].y : nc2[p].x;
            float vd = h ? dc2[p].y : dc2[p].x;
            vn += bperm(vn, a16); vd += bperm(vd, a16);
            vn += bperm(vn, a32); vd += bperm(vd, a32);
            if (lane < 16) {
                sn_w[wv][lane + (2 * p + h) * 16] = vn;
                sd_w[wv][lane + (2 * p + h) * 16] = vd;
            }
        }
    }
    __syncthreads();
    if (t < TJ) {
        size_t idx = (size_t)ib * NCOL + b * MM + j0 + t;
        numC[idx] = (sn_w[0][t] + sn_w[1][t]) + (sn_w[2][t] + sn_w[3][t]);
        denC[idx] = (sd_w[0][t] + sd_w[1][t]) + (sd_w[2][t] + sd_w[3][t]);
    }
}

__global__ __launch_bounds__(256)
void finalize2(const float* __restrict__ sR, const float* __restrict__ numR, const float* __restrict__ denR,
               const float* __restrict__ sC, const float* __restrict__ numC, const float* __restrict__ denC,
               float* __restrict__ bsum) {
    const int gid = blockIdx.x * 256 + threadIdx.x;   // 0..32767
    const float* S; const float* NU; const float* DE; int idx;
    if (gid < NROW) { S = sR; NU = numR; DE = denR; idx = gid; }
    else            { S = sC; NU = numC; DE = denC; idx = gid - NROW; }

    float m = 1e30f;
#pragma unroll 4
    for (int pb = 0; pb < 32; ++pb) m = fminf(m, S[(size_t)pb * NROW + idx]);
    float nu = 0.0f, de = 0.0f;
#pragma unroll 4
    for (int pb = 0; pb < 32; ++pb) {
        size_t o = (size_t)pb * NROW + idx;
        float f = __builtin_amdgcn_exp2f(m - S[o]);   // <= 0 arg
        nu = fmaf(NU[o], f, nu);
        de = fmaf(DE[o], f, de);
    }
    float q = nu * __builtin_amdgcn_rcpf(de);         // de >= 1

#pragma unroll
    for (int s = 1; s < 64; s <<= 1) q += __shfl_xor(q, s);
    __shared__ float wsum[4];
    const int t = threadIdx.x;
    if ((t & 63) == 0) wsum[t >> 6] = q;
    __syncthreads();
    if (t == 0) bsum[blockIdx.x] = (wsum[0] + wsum[1]) + (wsum[2] + wsum[3]);
}

__global__ __launch_bounds__(256)
void final_sum(const float* __restrict__ bsum, float* __restrict__ out) {
    const int t = threadIdx.x;
    float s = (t < 128) ? bsum[t] : 0.0f;
#pragma unroll
    for (int m = 1; m < 64; m <<= 1) s += __shfl_xor(s, m);
    __shared__ float wsum[4];
    if ((t & 63) == 0) wsum[t >> 6] = s;
    __syncthreads();
    if (t == 0) out[0] = (wsum[0] + wsum[1] + wsum[2] + wsum[3]) * (1.0f / (float)(BB * NN));
}

// ================= FALLBACK PATH (R13, 384KB ws) — unchanged =================
__device__ __forceinline__ void p1_quad(
    float& Xx, float& Xy, float& Xz, float& Xw,
    float& YxA, float& YyA, float& YzA, float& YwA,
    float& YxB, float& YyB, float& YzB, float& YwB,
    float& YxC, float& YyC, float& YzC, float& YwC,
    float& YxD, float& YyD, float& YzD, float& YwD,
    float& rm, float& cmA, float& cmB, float& cmC, float& cmD)
{
    float pA, pB, pC, pD;
    asm("v_add_f32 %[pA], %[Xw], %[YwA]\n\t"
        "v_add_f32 %[pB], %[Xw], %[YwB]\n\t"
        "v_add_f32 %[pC], %[Xw], %[YwC]\n\t"
        "v_add_f32 %[pD], %[Xw], %[YwD]\n\t"
        "v_fmac_f32 %[pA], %[Xz], %[YzA]\n\t"
        "v_fmac_f32 %[pB], %[Xz], %[YzB]\n\t"
        "v_fmac_f32 %[pC], %[Xz], %[YzC]\n\t"
        "v_fmac_f32 %[pD], %[Xz], %[YzD]\n\t"
        "v_fmac_f32 %[pA], %[Xy], %[YyA]\n\t"
        "v_fmac_f32 %[pB], %[Xy], %[YyB]\n\t"
        "v_fmac_f32 %[pC], %[Xy], %[YyC]\n\t"
        "v_fmac_f32 %[pD], %[Xy], %[YyD]\n\t"
        "v_fmac_f32 %[pA], %[Xx], %[YxA]\n\t"
        "v_fmac_f32 %[pB], %[Xx], %[YxB]\n\t"
        "v_fmac_f32 %[pC], %[Xx], %[YxC]\n\t"
        "v_fmac_f32 %[pD], %[Xx], %[YxD]\n\t"
        "v_min_f32 %[rm], %[rm], %[pA]\n\t"
        "v_min_f32 %[cmA], %[cmA], %[pA]\n\t"
        "v_min_f32 %[rm], %[rm], %[pB]\n\t"
        "v_min_f32 %[cmB], %[cmB], %[pB]\n\t"
        "v_min_f32 %[rm], %[rm], %[pC]\n\t"
        "v_min_f32 %[cmC], %[cmC], %[pC]\n\t"
        "v_min_f32 %[rm], %[rm], %[pD]\n\t"
        "v_min_f32 %[cmD], %[cmD], %[pD]"
        : [pA]"=&v"(pA), [pB]"=&v"(pB), [pC]"=&v"(pC), [pD]"=&v"(pD),
          [rm]"+v"(rm), [cmA]"+v"(cmA), [cmB]"+v"(cmB), [cmC]"+v"(cmC), [cmD]"+v"(cmD),
          [Xx]"+v"(Xx), [Xy]"+v"(Xy), [Xz]"+v"(Xz), [Xw]"+v"(Xw),
          [YxA]"+v"(YxA), [YyA]"+v"(YyA), [YzA]"+v"(YzA), [YwA]"+v"(YwA),
          [YxB]"+v"(YxB), [YyB]"+v"(YyB), [YzB]"+v"(YzB), [YwB]"+v"(YwB),
          [YxC]"+v"(YxC), [YyC]"+v"(YyC), [YzC]"+v"(YzC), [YwC]"+v"(YwC),
          [YxD]"+v"(YxD), [YyD]"+v"(YyD), [YzD]"+v"(YzD), [YwD]"+v"(YwD));
}

__device__ __forceinline__ void p2_quad(
    float& Xx, float& Xy, float& Xz, float& Xw, float& sr,
    float& YxA, float& YyA, float& YzA, float& YwA, float& scA,
    float& YxB, float& YyB, float& YzB, float& YwB, float& scB,
    float& YxC, float& YyC, float& YzC, float& YwC, float& scC,
    float& YxD, float& YyD, float& YzD, float& YwD, float& scD,
    float nL,
    float& nr, float& dr,
    float& ncA, float& dcA, float& ncB, float& dcB,
    float& ncC, float& dcC, float& ncD, float& dcD)
{
    float pA, pB, pC, pD, eA, eB, eC, eD;
    asm("v_add_f32 %[pA], %[Xw], %[YwA]\n\t"
        "v_add_f32 %[pB], %[Xw], %[YwB]\n\t"
        "v_add_f32 %[pC], %[Xw], %[YwC]\n\t"
        "v_add_f32 %[pD], %[Xw], %[YwD]\n\t"
        "v_fmac_f32 %[pA], %[Xz], %[YzA]\n\t"
        "v_fmac_f32 %[pB], %[Xz], %[YzB]\n\t"
        "v_fmac_f32 %[pC], %[Xz], %[YzC]\n\t"
        "v_fmac_f32 %[pD], %[Xz], %[YzD]\n\t"
        "v_fmac_f32 %[pA], %[Xy], %[YyA]\n\t"
        "v_fmac_f32 %[pB], %[Xy], %[YyB]\n\t"
        "v_fmac_f32 %[pC], %[Xy], %[YyC]\n\t"
        "v_fmac_f32 %[pD], %[Xy], %[YyD]\n\t"
        "v_fmac_f32 %[pA], %[Xx], %[YxA]\n\t"
        "v_fmac_f32 %[pB], %[Xx], %[YxB]\n\t"
        "v_fmac_f32 %[pC], %[Xx], %[YxC]\n\t"
        "v_fmac_f32 %[pD], %[Xx], %[YxD]\n\t"
        "v_max_f32 %[pA], 0, %[pA]\n\t"
        "v_max_f32 %[pB], 0, %[pB]\n\t"
        "v_max_f32 %[pC], 0, %[pC]\n\t"
        "v_max_f32 %[pD], 0, %[pD]\n\t"
        "v_sqrt_f32 %[pA], %[pA]\n\t"
        "v_sqrt_f32 %[pB], %[pB]\n\t"
        "v_sqrt_f32 %[pC], %[pC]\n\t"
        "v_sqrt_f32 %[pD], %[pD]\n\t"
        "v_fma_f32 %[eA], %[pA], %[nL], %[sr]\n\t"
        "v_fma_f32 %[eB], %[pB], %[nL], %[sr]\n\t"
        "v_fma_f32 %[eC], %[pC], %[nL], %[sr]\n\t"
        "v_fma_f32 %[eD], %[pD], %[nL], %[sr]\n\t"
        "v_exp_f32 %[eA], %[eA]\n\t"
        "v_exp_f32 %[eB], %[eB]\n\t"
        "v_exp_f32 %[eC], %[eC]\n\t"
        "v_exp_f32 %[eD], %[eD]\n\t"
        "v_fmac_f32 %[nr], %[pA], %[eA]\n\t"
        "v_add_f32 %[dr], %[dr], %[eA]\n\t"
        "v_fma_f32 %[eA], %[pA], %[nL], %[scA]\n\t"
        "v_fmac_f32 %[nr], %[pB], %[eB]\n\t"
        "v_add_f32 %[dr], %[dr], %[eB]\n\t"
        "v_fma_f32 %[eB], %[pB], %[nL], %[scB]\n\t"
        "v_fmac_f32 %[nr], %[pC], %[eC]\n\t"
        "v_add_f32 %[dr], %[dr], %[eC]\n\t"
        "v_fma_f32 %[eC], %[pC], %[nL], %[scC]\n\t"
        "v_fmac_f32 %[nr], %[pD], %[eD]\n\t"
        "v_add_f32 %[dr], %[dr], %[eD]\n\t"
        "v_fma_f32 %[eD], %[pD], %[nL], %[scD]\n\t"
        "v_exp_f32 %[eA], %[eA]\n\t"
        "v_exp_f32 %[eB], %[eB]\n\t"
        "v_exp_f32 %[eC], %[eC]\n\t"
        "v_exp_f32 %[eD], %[eD]\n\t"
        "v_fmac_f32 %[ncA], %[pA], %[eA]\n\t"
        "v_add_f32 %[dcA], %[dcA], %[eA]\n\t"
        "v_fmac_f32 %[ncB], %[pB], %[eB]\n\t"
        "v_add_f32 %[dcB], %[dcB], %[eB]\n\t"
        "v_fmac_f32 %[ncC], %[pC], %[eC]\n\t"
        "v_add_f32 %[dcC], %[dcC], %[eC]\n\t"
        "v_fmac_f32 %[ncD], %[pD], %[eD]\n\t"
        "v_add_f32 %[dcD], %[dcD], %[eD]"
        : [pA]"=&v"(pA), [pB]"=&v"(pB), [pC]"=&v"(pC), [pD]"=&v"(pD),
          [eA]"=&v"(eA), [eB]"=&v"(eB), [eC]"=&v"(eC), [eD]"=&v"(eD),
          [nr]"+v"(nr), [dr]"+v"(dr),
          [ncA]"+v"(ncA), [dcA]"+v"(dcA), [ncB]"+v"(ncB), [dcB]"+v"(dcB),
          [ncC]"+v"(ncC), [dcC]"+v"(dcC), [ncD]"+v"(ncD), [dcD]"+v"(dcD),
          [Xx]"+v"(Xx), [Xy]"+v"(Xy), [Xz]"+v"(Xz), [Xw]"+v"(Xw), [sr]"+v"(sr),
          [YxA]"+v"(YxA), [YyA]"+v"(YyA), [YzA]"+v"(YzA), [YwA]"+v"(YwA), [scA]"+v"(scA),
          [YxB]"+v"(YxB), [YyB]"+v"(YyB), [YzB]"+v"(YzB), [YwB]"+v"(YwB), [scB]"+v"(scB),
          [YxC]"+v"(YxC), [YyC]"+v"(YyC), [YzC]"+v"(YzC), [YwC]"+v"(YwC), [scC]"+v"(scC),
          [YxD]"+v"(YxD), [YyD]"+v"(YyD), [YzD]"+v"(YzD), [YwD]"+v"(YwD), [scD]"+v"(scD)
        : [nL]"s"(nL));
}

__global__ __launch_bounds__(256)
void init_ws_kernel(float* ws, float* out) {
    int idx = blockIdx.x * 256 + threadIdx.x;
    if (idx < 2 * 16384) ws[idx] = 1e30f;
    else if (idx < 6 * 16384) ws[idx] = 0.0f;
    if (idx == 0) out[0] = 0.0f;
}

__global__ __launch_bounds__(256)
void pass1_min(const float* __restrict__ x, const float* __restrict__ y,
               unsigned int* __restrict__ m2_row, unsigned int* __restrict__ m2_col) {
    const int bid = blockIdx.x;
    const int b   = bid / (NTI * NTJ);
    const int rem = bid % (NTI * NTJ);
    const int i0  = (rem / NTJ) * TI;
    const int j0  = (rem % NTJ) * TJ;

    __shared__ float4 xs4[TI];
    __shared__ float4 ys4[TJ];
    __shared__ float  cm_w[4][TJ];

    const int t = threadIdx.x;
    if (t < TI) xs4[t] = stage_x(&x[(size_t)(b * NN + i0 + t) * 3]);
    else        ys4[t - TI] = stage_y(&y[(size_t)(b * MM + j0 + (t - TI)) * 3]);
    __syncthreads();

    const int tx = t & 15, ty = t >> 4;
    const int lane = t & 63, wv = t >> 6;
    float Yx[8], Yy[8], Yz[8], Yw[8], cmin[8];
#pragma unroll
    for (int l = 0; l < 8; ++l) {
        float4 v = ys4[tx + l * 16];
        Yx[l] = v.x; Yy[l] = v.y; Yz[l] = v.z; Yw[l] = v.w;
        cmin[l] = 1e30f;
    }
#pragma unroll
    for (int k = 0; k < 8; ++k) {
        float4 Xv = xs4[ty + k * 16];
        float Xx = Xv.x, Xy = Xv.y, Xz = Xv.z, Xw = Xv.w;
        float rmin = 1e30f;
#pragma unroll
        for (int l = 0; l < 8; l += 4) {
            p1_quad(Xx, Xy, Xz, Xw,
                    Yx[l], Yy[l], Yz[l], Yw[l],
                    Yx[l+1], Yy[l+1], Yz[l+1], Yw[l+1],
                    Yx[l+2], Yy[l+2], Yz[l+2], Yw[l+2],
                    Yx[l+3], Yy[l+3], Yz[l+3], Yw[l+3],
                    rmin, cmin[l], cmin[l+1], cmin[l+2], cmin[l+3]);
        }
        rmin = dpp_min16(rmin);
        if (tx == 15) atomicMin(&m2_row[b * NN + i0 + ty + k * 16], __float_as_uint(rmin));
    }
    const int a16 = (lane ^ 16) << 2, a32 = (lane ^ 32) << 2;
#pragma unroll
    for (int l = 0; l < 8; ++l) {
        float v = cmin[l];
        v = fminf(v, bperm(v, a16));
        v = fminf(v, bperm(v, a32));
        if (lane < 16) cm_w[wv][lane + l * 16] = v;
    }
    __syncthreads();
    if (t < TJ) {
        float m = fminf(fminf(cm_w[0][t], cm_w[1][t]), fminf(cm_w[2][t], cm_w[3][t]));
        atomicMin(&m2_col[b * MM + j0 + t], __float_as_uint(m));
    }
}

__global__ __launch_bounds__(256)
void pass2_acc(const float* __restrict__ x, const float* __restrict__ y,
               const unsigned int* __restrict__ m2_row, const unsigned int* __restrict__ m2_col,
               float* __restrict__ num_r, float* __restrict__ den_r,
               float* __restrict__ num_c, float* __restrict__ den_c) {
    const int bid = blockIdx.x;
    const int b   = bid / (NTI * NTJ);
    const int rem = bid % (NTI * NTJ);
    const int i0  = (rem / NTJ) * TI;
    const int j0  = (rem % NTJ) * TJ;

    __shared__ float4 xs4[TI];
    __shared__ float4 ys4[TJ];
    __shared__ float  ar[TI];
    __shared__ float  ac[TJ];
    __shared__ float  sn_w[4][TJ];
    __shared__ float  sd_w[4][TJ];

    const int t = threadIdx.x;
    if (t < TI) {
        xs4[t] = stage_x(&x[(size_t)(b * NN + i0 + t) * 3]);
        ar[t]  = L2E100 * __builtin_amdgcn_sqrtf(fmaxf(__uint_as_float(m2_row[b * NN + i0 + t]), 0.0f));
    } else {
        int j = t - TI;
        ys4[j] = stage_y(&y[(size_t)(b * MM + j0 + j) * 3]);
        ac[j]  = L2E100 * __builtin_amdgcn_sqrtf(fmaxf(__uint_as_float(m2_col[b * MM + j0 + j]), 0.0f));
    }
    __syncthreads();

    const int tx = t & 15, ty = t >> 4;
    const int lane = t & 63, wv = t >> 6;
    const float nL = -L2E100;

    float Yx[8], Yy[8], Yz[8], Yw[8], sc[8], nc[8], dc[8];
#pragma unroll
    for (int l = 0; l < 8; ++l) {
        float4 v = ys4[tx + l * 16];
        Yx[l] = v.x; Yy[l] = v.y; Yz[l] = v.z; Yw[l] = v.w;
        sc[l] = ac[tx + l * 16];
        nc[l] = 0.0f; dc[l] = 0.0f;
    }
#pragma unroll
    for (int k = 0; k < 8; ++k) {
        float4 Xv = xs4[ty + k * 16];
        float Xx = Xv.x, Xy = Xv.y, Xz = Xv.z, Xw = Xv.w;
        float srk = ar[ty + k * 16];
        float nr = 0.0f, dr = 0.0f;
#pragma unroll
        for (int l = 0; l < 8; l += 4) {
            p2_quad(Xx, Xy, Xz, Xw, srk,
                    Yx[l], Yy[l], Yz[l], Yw[l], sc[l],
                    Yx[l+1], Yy[l+1], Yz[l+1], Yw[l+1], sc[l+1],
                    Yx[l+2], Yy[l+2], Yz[l+2], Yw[l+2], sc[l+2],
                    Yx[l+3], Yy[l+3], Yz[l+3], Yw[l+3], sc[l+3],
                    nL, nr, dr,
                    nc[l], dc[l], nc[l+1], dc[l+1],
                    nc[l+2], dc[l+2], nc[l+3], dc[l+3]);
        }
        float vn = dpp_sum16(nr);
        float vd = dpp_sum16(dr);
        if (tx == 15) {
            atomicAdd(&num_r[b * NN + i0 + ty + k * 16], vn);
            atomicAdd(&den_r[b * NN + i0 + ty + k * 16], vd);
        }
    }
    const int a16 = (lane ^ 16) << 2, a32 = (lane ^ 32) << 2;
#pragma unroll
    for (int l = 0; l < 8; ++l) {
        float vn = nc[l], vd = dc[l];
        vn += bperm(vn, a16); vd += bperm(vd, a16);
        vn += bperm(vn, a32); vd += bperm(vd, a32);
        if (lane < 16) { sn_w[wv][lane + l * 16] = vn; sd_w[wv][lane + l * 16] = vd; }
    }
    __syncthreads();
    if (t < TJ) {
        float ns = (sn_w[0][t] + sn_w[1][t]) + (sn_w[2][t] + sn_w[3][t]);
        float ds = (sd_w[0][t] + sd_w[1][t]) + (sd_w[2][t] + sd_w[3][t]);
        atomicAdd(&num_c[b * MM + j0 + t], ns);
        atomicAdd(&den_c[b * MM + j0 + t], ds);
    }
}

__global__ __launch_bounds__(256)
void finalize_kernel(const float* __restrict__ num_r, const float* __restrict__ den_r,
                     const float* __restrict__ num_c, const float* __restrict__ den_c,
                     float* __restrict__ out) {
    const int gid = blockIdx.x * 256 + threadIdx.x;
    float s = 0.0f;
    for (int idx = gid; idx < BB * NN; idx += 32 * 256) {
        s = fmaf(num_r[idx], __builtin_amdgcn_rcpf(den_r[idx]), s);
        s = fmaf(num_c[idx], __builtin_amdgcn_rcpf(den_c[idx]), s);
    }
#pragma unroll
    for (int m = 1; m < 64; m <<= 1) s += __shfl_xor(s, m);
    __shared__ float wsum[4];
    const int t = threadIdx.x;
    if ((t & 63) == 0) wsum[t >> 6] = s;
    __syncthreads();
    if (t == 0) {
        float v = (wsum[0] + wsum[1] + wsum[2] + wsum[3]) * (1.0f / (float)(BB * NN));
        atomicAdd(out, v);
    }
}

extern "C" void kernel_launch(void* const* d_in, const int* in_sizes, int n_in,
                              void* d_out, int out_size, void* d_ws, size_t ws_size,
                              hipStream_t stream) {
    const float* x = (const float*)d_in[0];
    const float* y = (const float*)d_in[1];
    float* ws = (float*)d_ws;

    const size_t PART = (size_t)32 * NROW;      // 524288 floats per partial array
    const size_t need = (6 * PART + 256) * sizeof(float);  // ~12.6MB

    if (ws_size >= need) {
        float* sR   = ws;
        float* numR = ws + PART;
        float* denR = ws + 2 * PART;
        float* sC   = ws + 3 * PART;
        float* numC = ws + 4 * PART;
        float* denC = ws + 5 * PART;
        float* bsum = ws + 6 * PART;

        hipLaunchKernelGGL(merged_pass, dim3(BB * NTI * NTJ), dim3(256), 0, stream,
                           x, y, sR, numR, denR, sC, numC, denC);
        hipLaunchKernelGGL(finalize2, dim3(128), dim3(256), 0, stream,
                           sR, numR, denR, sC, numC, denC, bsum);
        hipLaunchKernelGGL(final_sum, dim3(1), dim3(256), 0, stream, bsum, (float*)d_out);
    } else {
        unsigned int* m2_row = (unsigned int*)(ws);
        unsigned int* m2_col = (unsigned int*)(ws + 16384);
        float* num_r = ws + 32768;
        float* den_r = ws + 49152;
        float* num_c = ws + 65536;
        float* den_c = ws + 81920;

        hipLaunchKernelGGL(init_ws_kernel, dim3(384), dim3(256), 0, stream, ws, (float*)d_out);
        dim3 grid(BB * NTI * NTJ);
        hipLaunchKernelGGL(pass1_min, grid, dim3(256), 0, stream, x, y, m2_row, m2_col);
        hipLaunchKernelGGL(pass2_acc, grid, dim3(256), 0, stream,
                           x, y, m2_row, m2_col, num_r, den_r, num_c, den_c);
        hipLaunchKernelGGL(finalize_kernel, dim3(32), dim3(256), 0, stream,
                           num_r, den_r, num_c, den_c, (float*)d_out);
    }
}